// Round 2
// baseline (2221.459 us; speedup 1.0000x reference)
//
#include <hip/hip_runtime.h>
#include <hip/hip_fp8.h>

#define PTS 8192          // B*N = 4*2048 points
#define HDIM 512
#define BN_EPS 1e-4f
#define HSTRB 528         // LDS row stride in BYTES (fp8 cols)
#define TS 256.0f         // tangent-stream scale (keeps JVP streams out of e4m3 subnormals)
#define SCL1 0x7f7f7f7f   // E8M0 identity scale (1.0) for every 32-elem block

typedef unsigned short u16;
typedef unsigned char u8;
typedef long long i64;
typedef u16 u16x8 __attribute__((ext_vector_type(8)));
typedef short s16x8 __attribute__((ext_vector_type(8)));
typedef float f32x4 __attribute__((ext_vector_type(4)));
typedef float f32x2 __attribute__((ext_vector_type(2)));
typedef int i32x4 __attribute__((ext_vector_type(4)));
typedef int i32x8 __attribute__((ext_vector_type(8)));

__device__ __forceinline__ float bf2f(u16 u) {
  unsigned x = ((unsigned)u) << 16;
  return __builtin_bit_cast(float, x);
}
__device__ __forceinline__ u16 f2bf(float f) {
  unsigned x = __builtin_bit_cast(unsigned, f);
  x += 0x7fffu + ((x >> 16) & 1u);
  return (u16)(x >> 16);
}
// native HW fp8 convert (v_cvt_pk_fp8_f32; OCP e4m3 on gfx950)
__device__ __forceinline__ u8 f2f8(float x) {
  int v = __builtin_amdgcn_cvt_pk_fp8_f32(x, x, 0, false);
  return (u8)(v & 0xff);
}
__device__ __forceinline__ unsigned pk4_f8(float a, float b, float c, float d) {
  int v = __builtin_amdgcn_cvt_pk_fp8_f32(a, b, 0, false);
  v = __builtin_amdgcn_cvt_pk_fp8_f32(c, d, v, true);
  return (unsigned)v;
}
__device__ __forceinline__ float sigf(float x) {
  return __builtin_amdgcn_rcpf(1.f + __expf(-x));
}
__device__ __forceinline__ float fast_tanh(float x) {
  float e = __expf(2.f * x);
  return 1.f - 2.f * __builtin_amdgcn_rcpf(e + 1.f);
}
__device__ __forceinline__ void gl2lds16(const u16* g, u16* l) {
  __builtin_amdgcn_global_load_lds(
      (const __attribute__((address_space(1))) void*)g,
      (__attribute__((address_space(3))) void*)l, 16, 0, 0);
}
// 32B vector built from two 16B loads via clean SSA (no aliased alloca)
__device__ __forceinline__ i32x8 ld32(const u8* p) {
  i32x4 lo = *(const i32x4*)p;
  i32x4 hi = *(const i32x4*)(p + 16);
  return __builtin_shufflevector(lo, hi, 0, 1, 2, 3, 4, 5, 6, 7);
}

// ---------------------------------------------------------------- prep
struct PrepArgs {
  const float *W1, *W2;
  u8 *W1s, *W2s;       // fp8 e4m3, K=128 frag-order: [4 chunks][8 waves][4 j][64 lanes][32 B]
  const float* c;
  u16* cb;
  const float *Wg0, *Wg1, *Wg2, *Wb0, *Wb1, *Wb2;
  const float *bg0, *bg1, *bg2;
  u16* Wpack;          // [6*512][64] bf16
  float* bias_pack;    // [3072]
  const float *x, *m1, *v1, *lg1, *be1;
  float *x_cur;
  const float *Wg3, *bg3, *Wb3;
  float *G3, *B3;
  const float *W0, *b0, *b1, *b2, *W3;
  float *E0, *E1, *E2;   // packed epilogue params
};
__global__ void prep_kernel(PrepArgs a) {
  int i = blockIdx.x * 256 + threadIdx.x;   // 0 .. 524287
  if (i < 512 * 512) {
    int n = i >> 9, k = i & 511;
    int c = k >> 7, q2 = (k >> 5) & 3, b = k & 31;          // K=128 chunk / lane-group / byte
    int w = n >> 6, j = (n >> 4) & 3, lr = n & 15;
    size_t d = (size_t)c * 65536 + (size_t)w * 8192 + (size_t)j * 2048 +
               (size_t)(q2 * 16 + lr) * 32 + b;
    a.W1s[d] = f2f8(a.W1[i]);
    a.W2s[d] = f2f8(a.W2[i]);
  }
  if (i < PTS * 64) a.cb[i] = f2bf(a.c[i]);
  if (i < 6 * 512 * 64) {
    int sec = i >> 15;
    int within = i & 32767;
    int o = within >> 6, k = within & 63;
    const float* src[6] = {a.Wg0, a.Wg1, a.Wg2, a.Wb0, a.Wb1, a.Wb2};
    a.Wpack[i] = f2bf(src[sec][o * 65 + 1 + k]);
  }
  if (i < 3072) {
    int sec = i >> 9, o = i & 511;
    const float* bgl[3] = {a.bg0, a.bg1, a.bg2};
    a.bias_pack[i] = (sec < 3) ? bgl[sec][o] : 0.f;
  }
  if (i < 512) {
    int o = i;
    a.E0[o * 8 + 0] = a.W0[o * 3];
    a.E0[o * 8 + 1] = a.W0[o * 3 + 1];
    a.E0[o * 8 + 2] = a.W0[o * 3 + 2];
    a.E0[o * 8 + 3] = a.b0[o];
    a.E0[o * 8 + 4] = a.Wg0[o * 65];
    a.E0[o * 8 + 5] = a.Wb0[o * 65];
    a.E0[o * 8 + 6] = 0.f; a.E0[o * 8 + 7] = 0.f;
    a.E1[o * 4 + 0] = a.b1[o];
    a.E1[o * 4 + 1] = a.Wg1[o * 65];
    a.E1[o * 4 + 2] = a.Wb1[o * 65];
    a.E1[o * 4 + 3] = 0.f;
    a.E2[o * 8 + 0] = a.b2[o];
    a.E2[o * 8 + 1] = a.Wg2[o * 65];
    a.E2[o * 8 + 2] = a.Wb2[o * 65];
    a.E2[o * 8 + 3] = a.W3[o];
    a.E2[o * 8 + 4] = a.W3[512 + o];
    a.E2[o * 8 + 5] = a.W3[1024 + o];
    a.E2[o * 8 + 6] = 0.f; a.E2[o * 8 + 7] = 0.f;
  }
  if (i < PTS * 3) {
    int d = i % 3;
    a.x_cur[i] = (a.x[i] - a.m1[d]) * __expf(a.lg1[d]) * rsqrtf(a.v1[d] + BN_EPS) + a.be1[d];
  }
  {
    int lane = threadIdx.x & 63;
    int p = (blockIdx.x * 256 + threadIdx.x) >> 6;   // 0..8191
    float cv = a.c[(size_t)p * 64 + lane];
    float ag[3], ab[3];
    #pragma unroll
    for (int o = 0; o < 3; ++o) {
      ag[o] = cv * a.Wg3[o * 65 + 1 + lane];
      ab[o] = cv * a.Wb3[o * 65 + 1 + lane];
    }
    #pragma unroll
    for (int off = 32; off > 0; off >>= 1) {
      #pragma unroll
      for (int o = 0; o < 3; ++o) {
        ag[o] += __shfl_xor(ag[o], off);
        ab[o] += __shfl_xor(ab[o], off);
      }
    }
    if (lane == 0) {
      #pragma unroll
      for (int o = 0; o < 3; ++o) {
        a.G3[p * 3 + o] = ag[o] + a.bg3[o];
        a.B3[p * 3 + o] = ab[o];
      }
    }
  }
}

// ---------------------------------------------------------------- gates GEMM (bf16, proven)
struct GatesGemmArgs {
  const u16 *A, *W;
  const float* bias;
  u16* GBi;                // [3][8192][1024] interleaved
};
__global__ __launch_bounds__(256) void gates_gemm(GatesGemmArgs a) {
  __shared__ u16 As[128 * 32];
  __shared__ u16 Bs[128 * 32];
  int tid = threadIdx.x;
  int m0 = blockIdx.x * 128, n0 = blockIdx.y * 128;
  int wave = tid >> 6, lane = tid & 63;
  int wm = (wave & 1) * 64, wn = (wave >> 1) * 64;
  int lr = lane & 15, quad = lane >> 4;

  int rowS = tid >> 2, colS = (tid & 3) * 8;
  const u16* gA0 = a.A + (size_t)(m0 + rowS) * 64 + colS;
  const u16* gB0 = a.W + (size_t)(n0 + rowS) * 64 + colS;
  u16* sA0 = &As[tid * 8];
  u16* sA1 = &As[2048 + tid * 8];
  u16* sB0 = &Bs[tid * 8];
  u16* sB1 = &Bs[2048 + tid * 8];

  f32x4 acc[4][4];
  #pragma unroll
  for (int i = 0; i < 4; ++i)
    #pragma unroll
    for (int j = 0; j < 4; ++j)
      #pragma unroll
      for (int r = 0; r < 4; ++r) acc[i][j][r] = 0.f;

  for (int k0 = 0; k0 < 64; k0 += 32) {
    if (k0) __syncthreads();
    gl2lds16(gA0 + k0, sA0);
    gl2lds16(gA0 + (size_t)64 * 64 + k0, sA1);
    gl2lds16(gB0 + k0, sB0);
    gl2lds16(gB0 + (size_t)64 * 64 + k0, sB1);
    __syncthreads();
    s16x8 af[4], bfr[4];
    #pragma unroll
    for (int i = 0; i < 4; ++i)
      af[i] = *(const s16x8*)&As[(wm + i * 16 + lr) * 32 + quad * 8];
    #pragma unroll
    for (int j = 0; j < 4; ++j)
      bfr[j] = *(const s16x8*)&Bs[(wn + j * 16 + lr) * 32 + quad * 8];
    #pragma unroll
    for (int i = 0; i < 4; ++i)
      #pragma unroll
      for (int j = 0; j < 4; ++j)
        acc[i][j] = __builtin_amdgcn_mfma_f32_16x16x32_bf16(af[i], bfr[j], acc[i][j], 0, 0, 0);
  }

  #pragma unroll
  for (int j = 0; j < 4; ++j) {
    int n = n0 + wn + j * 16 + lr;
    int sec = n >> 9, col = n & 511;
    int l = (sec < 3) ? sec : sec - 3;
    int off = col * 2 + ((sec < 3) ? 0 : 1);
    float bv = a.bias[n];
    u16* outp = a.GBi + (size_t)l * PTS * 1024 + off;
    #pragma unroll
    for (int i = 0; i < 4; ++i) {
      int mrow = m0 + wm + i * 16 + quad * 4;
      #pragma unroll
      for (int r = 0; r < 4; ++r)
        outp[(size_t)(mrow + r) * 1024] = f2bf(acc[i][j][r] + bv);
    }
  }
}

// ---------------------------------------------------------------- fused 12-stage flow kernel
// 512 blocks x 512 threads (8 waves); block owns 16 points (64 m-rows) for the WHOLE
// RK4 integration: all inter-stage state lives in LDS.  GEMMs use MX-scaled fp8 MFMA
// (K=128, identity scales).  Register discipline: peak live <= ~114 of the 128 cap —
// B held as a j-PAIR (16 regs), schedule pinned with sched_barrier + asm fences so the
// compiler cannot hoist B prefetches / CSE A-frag reads into extra live registers
// (round-1 lesson: that hoisting caused ~35-reg spill -> 693 MB scratch writes).
struct FlowArgs {
  const float* sqrtT;
  const float *G3, *B3, *Wg3, *Wb3, *b3;
  const float* x0;                 // BN1-applied initial x
  const u16 *GBi0, *GBi1, *GBi2;   // interleaved gate tables [PTS][1024]
  const float *E0, *E1, *E2;       // packed params
  const u8 *W1s, *W2s;             // fp8 weights K=128 frag-order [4][8][4][64][32]
  const float *m2, *v2, *lg2, *be2;
  float* out_x;
  float* lp_state;
};

__device__ __forceinline__ void mx_gemm(const u8* wl, const u8* hb, f32x4 acc[4][4]) {
  #pragma unroll
  for (int i = 0; i < 4; ++i)
    #pragma unroll
    for (int j = 0; j < 4; ++j)
      #pragma unroll
      for (int r = 0; r < 4; ++r) acc[i][j][r] = 0.f;

  const u8* wp = wl;
  i32x8 bA = ld32(wp);
  i32x8 bB = ld32(wp + 2048);
  #pragma unroll 1
  for (int c = 0; c < 4; ++c) {
    const u8* hc = hb + c * 128;
    // ---- half 1: j = 0,1
    __builtin_amdgcn_s_setprio(1);
    #pragma unroll
    for (int i = 0; i < 4; ++i) {
      i32x8 af = ld32(hc + (size_t)i * (16 * HSTRB));
      acc[i][0] = __builtin_amdgcn_mfma_scale_f32_16x16x128_f8f6f4(
          af, bA, acc[i][0], 0, 0, 0, SCL1, 0, SCL1);
      acc[i][1] = __builtin_amdgcn_mfma_scale_f32_16x16x128_f8f6f4(
          af, bB, acc[i][1], 0, 0, 0, SCL1, 0, SCL1);
    }
    __builtin_amdgcn_s_setprio(0);
    __builtin_amdgcn_sched_barrier(0);
    asm volatile("" ::: "memory");   // kill CSE of A-frags + pin B loads below MFMAs
    bA = ld32(wp + 2 * 2048);
    bB = ld32(wp + 3 * 2048);
    // ---- half 2: j = 2,3
    __builtin_amdgcn_s_setprio(1);
    #pragma unroll
    for (int i = 0; i < 4; ++i) {
      i32x8 af = ld32(hc + (size_t)i * (16 * HSTRB));
      acc[i][2] = __builtin_amdgcn_mfma_scale_f32_16x16x128_f8f6f4(
          af, bA, acc[i][2], 0, 0, 0, SCL1, 0, SCL1);
      acc[i][3] = __builtin_amdgcn_mfma_scale_f32_16x16x128_f8f6f4(
          af, bB, acc[i][3], 0, 0, 0, SCL1, 0, SCL1);
    }
    __builtin_amdgcn_s_setprio(0);
    __builtin_amdgcn_sched_barrier(0);
    asm volatile("" ::: "memory");
    if (c < 3) {
      wp += 65536;
      bA = ld32(wp);
      bB = ld32(wp + 2048);
    }
  }
}

__global__ __launch_bounds__(512, 4) void flow_kernel(FlowArgs a) {
  __shared__ __align__(16) u8 Hs[64 * HSTRB];     // 33.8 KB (fp8 activations)
  __shared__ float xe[16][3];
  __shared__ float part[8][16][6];
  __shared__ float xs[16][3], kxs[16][3];
  __shared__ float kls[16], lps[16];
  __shared__ float g3s[16][3], b3s[16][3];

  int tid = threadIdx.x;
  int w = tid >> 6, lane = tid & 63, lr = lane & 15, quad = lane >> 4;
  int n0 = w * 64;
  int p0 = blockIdx.x * 16;
  float s0 = a.sqrtT[0];
  float dt = s0 * s0 * (1.f / 3.f);

  // wave-local W slice base pointers (K=128 frag-order)
  const u8* w1l = a.W1s + (size_t)w * 8192 + (size_t)lane * 32;
  const u8* w2l = a.W2s + (size_t)w * 8192 + (size_t)lane * 32;
  const u8* hb = (const u8*)Hs + (size_t)lr * HSTRB + quad * 32;

  float wg3r[3], wb3r[3], b3r[3];
  #pragma unroll
  for (int r = 0; r < 3; ++r) {
    wg3r[r] = a.Wg3[r * 65];
    wb3r[r] = a.Wb3[r * 65];
    b3r[r] = a.b3[r];
  }

  if (tid < 16) {
    int p = p0 + tid;
    #pragma unroll
    for (int r = 0; r < 3; ++r) {
      xs[tid][r] = a.x0[p * 3 + r];
      g3s[tid][r] = a.G3[p * 3 + r];
      b3s[tid][r] = a.B3[p * 3 + r];
    }
    lps[tid] = 0.f;
  }

  int pl0 = tid >> 5;
  int base_o = (tid & 31) * 16;
  const u16* g0row = a.GBi0 + (size_t)(p0 + pl0) * 1024 + 2 * base_o;

  #pragma unroll 1
  for (int s = 0; s < 12; ++s) {
    int sub = s & 3;
    float ts_cur = (float)(s >> 2) + ((sub == 0) ? 0.f : (sub == 3) ? 1.f : 0.5f);

    // issue L0 gate loads early (L2-hot after stage 0)
    u16x8 gc0 = *(const u16x8*)(g0row);
    u16x8 gc1 = *(const u16x8*)(g0row + 8);
    u16x8 gc2 = *(const u16x8*)(g0row + 16);
    u16x8 gc3 = *(const u16x8*)(g0row + 24);

    __syncthreads();   // s==0: init visible; s>0: part[] from prev stage visible

    // ---- fold previous stage (thread per point; all state in LDS)
    if (tid < 16) {
      float o0 = xs[tid][0], o1 = xs[tid][1], o2 = xs[tid][2];
      if (s > 0) {
        int m = (s - 1) & 3;
        float ts_prev = (float)((s - 1) >> 2) + ((m == 0) ? 0.f : (m == 3) ? 1.f : 0.5f);
        float tp = ts_prev * dt;
        float fr[6];
        #pragma unroll
        for (int r = 0; r < 6; ++r) {
          float sum = part[0][tid][r];
          #pragma unroll
          for (int ww = 1; ww < 8; ++ww) sum += part[ww][tid][r];
          fr[r] = sum;
        }
        float dx[3], gate[3];
        #pragma unroll
        for (int r = 0; r < 3; ++r) {
          gate[r] = sigf(g3s[tid][r] + tp * wg3r[r]);
          float bias = b3s[tid][r] + tp * wb3r[r];
          dx[r] = fmaf(fr[r] + b3r[r], gate[r], bias);
        }
        float klv = -(fr[3] * gate[0] + fr[4] * gate[1] + fr[5] * gate[2]);
        if (m == 0) {
          o0 += 0.5f * dt * dx[0]; o1 += 0.5f * dt * dx[1]; o2 += 0.5f * dt * dx[2];
          kxs[tid][0] = dx[0]; kxs[tid][1] = dx[1]; kxs[tid][2] = dx[2];
          kls[tid] = klv;
        } else if (m == 1) {
          o0 += 0.5f * dt * dx[0]; o1 += 0.5f * dt * dx[1]; o2 += 0.5f * dt * dx[2];
          kxs[tid][0] += 2.f * dx[0]; kxs[tid][1] += 2.f * dx[1]; kxs[tid][2] += 2.f * dx[2];
          kls[tid] += 2.f * klv;
        } else if (m == 2) {
          o0 += dt * dx[0]; o1 += dt * dx[1]; o2 += dt * dx[2];
          kxs[tid][0] += 2.f * dx[0]; kxs[tid][1] += 2.f * dx[1]; kxs[tid][2] += 2.f * dx[2];
          kls[tid] += 2.f * klv;
        } else {
          float sc = dt * (1.f / 6.f);
          o0 = xs[tid][0] + sc * (kxs[tid][0] + dx[0]);
          o1 = xs[tid][1] + sc * (kxs[tid][1] + dx[1]);
          o2 = xs[tid][2] + sc * (kxs[tid][2] + dx[2]);
          xs[tid][0] = o0; xs[tid][1] = o1; xs[tid][2] = o2;
          lps[tid] += sc * (kls[tid] + klv);
        }
      }
      xe[tid][0] = o0; xe[tid][1] = o1; xe[tid][2] = o2;
    }
    __syncthreads();

    float t = ts_cur * dt;

    // ---- layer0: 32 threads per point, 16 cols each -> H1 (fp8) in LDS
    {
      float x0v = xe[pl0][0], x1v = xe[pl0][1], x2v = xe[pl0][2];
      u16x8 gcv[4] = {gc0, gc1, gc2, gc3};
      #pragma unroll
      for (int cc = 0; cc < 4; ++cc) {
        u16x8 v = gcv[cc];
        float hk[4], d0k[4], d1k[4], d2k[4];
        #pragma unroll
        for (int k = 0; k < 4; ++k) {
          int o = base_o + cc * 4 + k;
          f32x4 e = *(const f32x4*)(a.E0 + (size_t)o * 8);
          f32x2 e2 = *(const f32x2*)(a.E0 + (size_t)o * 8 + 4);
          float u = fmaf(e[0], x0v, fmaf(e[1], x1v, e[2] * x2v)) + e[3];
          float gate = sigf(bf2f(v[2 * k]) + t * e2[0]);
          float bias = bf2f(v[2 * k + 1]) + t * e2[1];
          float z = fmaf(u, gate, bias);
          float h = fast_tanh(z);
          float wm = (1.f - h * h) * gate * TS;
          hk[k] = h;
          d0k[k] = wm * e[0];
          d1k[k] = wm * e[1];
          d2k[k] = wm * e[2];
        }
        size_t hbb = (size_t)(pl0 * 4) * HSTRB + base_o + cc * 4;
        *(unsigned*)(Hs + hbb) = pk4_f8(hk[0], hk[1], hk[2], hk[3]);
        *(unsigned*)(Hs + hbb + HSTRB) = pk4_f8(d0k[0], d0k[1], d0k[2], d0k[3]);
        *(unsigned*)(Hs + hbb + 2 * HSTRB) = pk4_f8(d1k[0], d1k[1], d1k[2], d1k[3]);
        *(unsigned*)(Hs + hbb + 3 * HSTRB) = pk4_f8(d2k[0], d2k[1], d2k[2], d2k[3]);
      }
    }
    __syncthreads();   // H1 visible to all waves

    // ---- GEMM1: MX fp8 K=128, j-pair schedule, no in-loop barriers
    f32x4 acc[4][4];
    mx_gemm(w1l, hb, acc);

    // epilogue-1 gate dwords: load into just-freed B registers; latency hides
    // behind the barrier drain + other waves
    unsigned g1v[4][4];
    #pragma unroll
    for (int j = 0; j < 4; ++j)
      #pragma unroll
      for (int i = 0; i < 4; ++i)
        g1v[j][i] = *(const unsigned*)(a.GBi1 + (size_t)(p0 + i * 4 + quad) * 1024 +
                                       2 * (n0 + j * 16 + lr));

    __syncthreads();   // all H1 reads done -> safe to overwrite

    // ---- epilogue1 -> H2 (fp8) in same LDS
    #pragma unroll
    for (int j = 0; j < 4; ++j) {
      int n = n0 + j * 16 + lr;
      f32x4 e1 = *(const f32x4*)(a.E1 + (size_t)n * 4);
      #pragma unroll
      for (int i = 0; i < 4; ++i) {
        unsigned d = g1v[j][i];
        float gate = sigf(bf2f((u16)(d & 0xffffu)) + t * e1[1]);
        float bias = bf2f((u16)(d >> 16)) + t * e1[2];
        f32x4 u = acc[i][j];
        float z = fmaf(u[0] + e1[0], gate, bias);
        float h = fast_tanh(z);
        float wmf = (1.f - h * h) * gate;
        int row = i * 16 + quad * 4;
        Hs[(size_t)row * HSTRB + n] = f2f8(h);
        Hs[(size_t)(row + 1) * HSTRB + n] = f2f8(u[1] * wmf);
        Hs[(size_t)(row + 2) * HSTRB + n] = f2f8(u[2] * wmf);
        Hs[(size_t)(row + 3) * HSTRB + n] = f2f8(u[3] * wmf);
      }
    }
    __syncthreads();   // H2 visible

    // ---- GEMM2
    mx_gemm(w2l, hb, acc);

    unsigned g2v[4][4];
    #pragma unroll
    for (int j = 0; j < 4; ++j)
      #pragma unroll
      for (int i = 0; i < 4; ++i)
        g2v[j][i] = *(const unsigned*)(a.GBi2 + (size_t)(p0 + i * 4 + quad) * 1024 +
                                       2 * (n0 + j * 16 + lr));

    // ---- epilogue2: gate/tanh + project onto W3 -> 6 partials per point
    #pragma unroll
    for (int i = 0; i < 4; ++i) {
      float v0 = 0.f, v1 = 0.f, v2 = 0.f, v3 = 0.f, v4 = 0.f, v5 = 0.f;
      int pl = i * 4 + quad;
      #pragma unroll
      for (int j = 0; j < 4; ++j) {
        int n = n0 + j * 16 + lr;
        f32x4 ea = *(const f32x4*)(a.E2 + (size_t)n * 8);
        f32x2 eb = *(const f32x2*)(a.E2 + (size_t)n * 8 + 4);
        unsigned d = g2v[j][i];
        float gate = sigf(bf2f((u16)(d & 0xffffu)) + t * ea[1]);
        float bias = bf2f((u16)(d >> 16)) + t * ea[2];
        f32x4 u = acc[i][j];
        float z = fmaf(u[0] + ea[0], gate, bias);
        float h = fast_tanh(z);
        float wmf = (1.f - h * h) * gate;
        float w30 = ea[3], w31 = eb[0], w32 = eb[1];
        v0 = fmaf(h, w30, v0);
        v1 = fmaf(h, w31, v1);
        v2 = fmaf(h, w32, v2);
        v3 = fmaf(u[1] * wmf, w30, v3);
        v4 = fmaf(u[2] * wmf, w31, v4);
        v5 = fmaf(u[3] * wmf, w32, v5);
      }
      #pragma unroll
      for (int mask = 1; mask <= 8; mask <<= 1) {
        v0 += __shfl_xor(v0, mask);
        v1 += __shfl_xor(v1, mask);
        v2 += __shfl_xor(v2, mask);
        v3 += __shfl_xor(v3, mask);
        v4 += __shfl_xor(v4, mask);
        v5 += __shfl_xor(v5, mask);
      }
      // tangent streams carry TS scale through both GEMMs -> undo here
      float val = (lr == 0) ? v0 : (lr == 1) ? v1 : (lr == 2) ? v2
                : (lr == 3) ? v3 * (1.f / TS) : (lr == 4) ? v4 * (1.f / TS)
                : v5 * (1.f / TS);
      if (lr < 6) part[w][pl][lr] = val;
    }
  }  // stage loop

  __syncthreads();   // stage-11 partials visible

  // ---- final fold (mode 3 at t=T) + BN2 + store
  if (tid < 16) {
    int p = p0 + tid;
    float tp = 3.f * dt;
    float fr[6];
    #pragma unroll
    for (int r = 0; r < 6; ++r) {
      float sum = part[0][tid][r];
      #pragma unroll
      for (int ww = 1; ww < 8; ++ww) sum += part[ww][tid][r];
      fr[r] = sum;
    }
    float dx[3], gate[3];
    #pragma unroll
    for (int r = 0; r < 3; ++r) {
      gate[r] = sigf(g3s[tid][r] + tp * wg3r[r]);
      float bias = b3s[tid][r] + tp * wb3r[r];
      dx[r] = fmaf(fr[r] + b3r[r], gate[r], bias);
    }
    float klv = -(fr[3] * gate[0] + fr[4] * gate[1] + fr[5] * gate[2]);
    float sc = dt * (1.f / 6.f);
    #pragma unroll
    for (int r = 0; r < 3; ++r) {
      float xf = xs[tid][r] + sc * (kxs[tid][r] + dx[r]);
      a.out_x[p * 3 + r] =
          (xf - a.m2[r]) * __expf(a.lg2[r]) * rsqrtf(a.v2[r] + BN_EPS) + a.be2[r];
    }
    a.lp_state[p] = lps[tid] + sc * (kls[tid] + klv);
  }
}

__global__ void finish_lp(const float* __restrict__ lp_state,
                          const float* __restrict__ v1, const float* __restrict__ lg1,
                          const float* __restrict__ v2, const float* __restrict__ lg2,
                          float* __restrict__ out) {
  int b = blockIdx.x, tid = threadIdx.x;
  float s = 0.f;
  for (int n = tid; n < 2048; n += 256) s += lp_state[b * 2048 + n];
  __shared__ float red[256];
  red[tid] = s;
  __syncthreads();
  for (int w = 128; w > 0; w >>= 1) {
    if (tid < w) red[tid] += red[tid + w];
    __syncthreads();
  }
  if (tid == 0) {
    float ld = 0.f;
    for (int d = 0; d < 3; ++d) {
      ld += lg1[d] - 0.5f * logf(v1[d] + BN_EPS);
      ld += lg2[d] - 0.5f * logf(v2[d] + BN_EPS);
    }
    out[b] = red[0] - 2048.f * ld;
  }
}

// ---------------------------------------------------------------- launch
extern "C" void kernel_launch(void* const* d_in, const int* in_sizes, int n_in,
                              void* d_out, int out_size, void* d_ws, size_t ws_size,
                              hipStream_t stream) {
  const float* x        = (const float*)d_in[0];
  const float* c        = (const float*)d_in[1];
  const float* bn1_mean = (const float*)d_in[2];
  const float* bn1_var  = (const float*)d_in[3];
  const float* bn1_lg   = (const float*)d_in[4];
  const float* bn1_beta = (const float*)d_in[5];
  const float* bn2_mean = (const float*)d_in[6];
  const float* bn2_var  = (const float*)d_in[7];
  const float* bn2_lg   = (const float*)d_in[8];
  const float* bn2_beta = (const float*)d_in[9];
  const float* sqrtT    = (const float*)d_in[10];
  const float* W0  = (const float*)d_in[11];
  const float* b0  = (const float*)d_in[12];
  const float* Wg0 = (const float*)d_in[13];
  const float* bg0 = (const float*)d_in[14];
  const float* Wb0 = (const float*)d_in[15];
  const float* W1  = (const float*)d_in[16];
  const float* b1  = (const float*)d_in[17];
  const float* Wg1 = (const float*)d_in[18];
  const float* bg1 = (const float*)d_in[19];
  const float* Wb1 = (const float*)d_in[20];
  const float* W2  = (const float*)d_in[21];
  const float* b2  = (const float*)d_in[22];
  const float* Wg2 = (const float*)d_in[23];
  const float* bg2 = (const float*)d_in[24];
  const float* Wb2 = (const float*)d_in[25];
  const float* W3  = (const float*)d_in[26];
  const float* b3  = (const float*)d_in[27];
  const float* Wg3 = (const float*)d_in[28];
  const float* bg3 = (const float*)d_in[29];
  const float* Wb3 = (const float*)d_in[30];

  char* base = (char*)d_ws;
  size_t off = 0;
  auto alloc = [&](size_t bytes) -> void* {
    void* pp = base + off;
    off += (bytes + 255) & ~(size_t)255;
    return pp;
  };
  u8* W1s = (u8*)alloc((size_t)512 * 512);
  u8* W2s = (u8*)alloc((size_t)512 * 512);
  u16* cb  = (u16*)alloc((size_t)PTS * 64 * 2);
  u16* Wpack = (u16*)alloc((size_t)6 * 512 * 64 * 2);
  float* bias_pack = (float*)alloc((size_t)3072 * 4);
  u16* GBi = (u16*)alloc((size_t)3 * PTS * 1024 * 2);
  const size_t SZi = (size_t)PTS * 1024;
  u16* GBi0 = GBi;
  u16* GBi1 = GBi + SZi;
  u16* GBi2 = GBi + 2 * SZi;
  float* G3f = (float*)alloc((size_t)PTS * 3 * 4);
  float* B3f = (float*)alloc((size_t)PTS * 3 * 4);
  float* E0 = (float*)alloc((size_t)512 * 8 * 4);
  float* E1 = (float*)alloc((size_t)512 * 4 * 4);
  float* E2 = (float*)alloc((size_t)512 * 8 * 4);
  float* x_cur    = (float*)alloc((size_t)PTS * 3 * 4);
  float* lp_state = (float*)alloc((size_t)PTS * 4);
  (void)ws_size; (void)in_sizes; (void)n_in; (void)out_size;

  PrepArgs pa{W1, W2, W1s, W2s, c, cb, Wg0, Wg1, Wg2, Wb0, Wb1, Wb2,
              bg0, bg1, bg2, Wpack, bias_pack, x, bn1_mean, bn1_var,
              bn1_lg, bn1_beta, x_cur, Wg3, bg3, Wb3, G3f, B3f,
              W0, b0, b1, b2, W3, E0, E1, E2};
  prep_kernel<<<2048, 256, 0, stream>>>(pa);

  GatesGemmArgs gg{cb, Wpack, bias_pack, GBi};
  gates_gemm<<<dim3(64, 24), 256, 0, stream>>>(gg);

  FlowArgs fa{sqrtT, G3f, B3f, Wg3, Wb3, b3, x_cur, GBi0, GBi1, GBi2,
              E0, E1, E2, W1s, W2s, bn2_mean, bn2_var, bn2_lg, bn2_beta,
              (float*)d_out, lp_state};
  flow_kernel<<<PTS / 16, 512, 0, stream>>>(fa);

  finish_lp<<<4, 256, 0, stream>>>(lp_state, bn1_var, bn1_lg, bn2_var, bn2_lg,
                                   (float*)d_out + PTS * 3);
}

// Round 3
// 563.836 us; speedup vs baseline: 3.9399x; 3.9399x over previous
//
#include <hip/hip_runtime.h>
#include <hip/hip_fp8.h>

#define PTS 8192          // B*N = 4*2048 points
#define HDIM 512
#define BN_EPS 1e-4f
#define HSTRB 528         // LDS row stride in BYTES (fp8 cols)
#define TS 256.0f         // tangent-stream scale (keeps JVP streams out of e4m3 subnormals)
#define SCL1 0x7f7f7f7f   // E8M0 identity scale (1.0) for every 32-elem block

typedef unsigned short u16;
typedef unsigned char u8;
typedef long long i64;
typedef u16 u16x8 __attribute__((ext_vector_type(8)));
typedef short s16x8 __attribute__((ext_vector_type(8)));
typedef float f32x4 __attribute__((ext_vector_type(4)));
typedef float f32x2 __attribute__((ext_vector_type(2)));
typedef int i32x4 __attribute__((ext_vector_type(4)));
typedef int i32x8 __attribute__((ext_vector_type(8)));

__device__ __forceinline__ float bf2f(u16 u) {
  unsigned x = ((unsigned)u) << 16;
  return __builtin_bit_cast(float, x);
}
__device__ __forceinline__ u16 f2bf(float f) {
  unsigned x = __builtin_bit_cast(unsigned, f);
  x += 0x7fffu + ((x >> 16) & 1u);
  return (u16)(x >> 16);
}
// native HW fp8 convert (v_cvt_pk_fp8_f32; OCP e4m3 on gfx950)
__device__ __forceinline__ u8 f2f8(float x) {
  int v = __builtin_amdgcn_cvt_pk_fp8_f32(x, x, 0, false);
  return (u8)(v & 0xff);
}
__device__ __forceinline__ unsigned pk4_f8(float a, float b, float c, float d) {
  int v = __builtin_amdgcn_cvt_pk_fp8_f32(a, b, 0, false);
  v = __builtin_amdgcn_cvt_pk_fp8_f32(c, d, v, true);
  return (unsigned)v;
}
__device__ __forceinline__ float sigf(float x) {
  return __builtin_amdgcn_rcpf(1.f + __expf(-x));
}
__device__ __forceinline__ float fast_tanh(float x) {
  float e = __expf(2.f * x);
  return 1.f - 2.f * __builtin_amdgcn_rcpf(e + 1.f);
}
__device__ __forceinline__ void gl2lds16(const u16* g, u16* l) {
  __builtin_amdgcn_global_load_lds(
      (const __attribute__((address_space(1))) void*)g,
      (__attribute__((address_space(3))) void*)l, 16, 0, 0);
}
// 32B vector built from two 16B loads via clean SSA (no aliased alloca)
__device__ __forceinline__ i32x8 ld32(const u8* p) {
  i32x4 lo = *(const i32x4*)p;
  i32x4 hi = *(const i32x4*)(p + 16);
  return __builtin_shufflevector(lo, hi, 0, 1, 2, 3, 4, 5, 6, 7);
}

#define MFMA_SC(A, B, C) \
  __builtin_amdgcn_mfma_scale_f32_16x16x128_f8f6f4((A), (B), (C), 0, 0, 0, SCL1, 0, SCL1)

// MX K=128 GEMM, j-pair B schedule.  VGPR budget: af0..af3 (32) + bA,bB (16) +
// addressing (~10) < 64; acc[4][4] lives in AGPRs.  sched_barrier(0) (intrinsic,
// NO memory semantics) pins the B reloads below the preceding MFMA cluster so the
// scheduler cannot double-buffer them into extra live registers.  NO asm clobbers
// anywhere (round-2 lesson: "memory" clobber forced acc's alloca to scratch).
#define MX_GEMM(WL)                                                         \
  {                                                                         \
    _Pragma("unroll")                                                       \
    for (int zi = 0; zi < 4; ++zi)                                          \
      _Pragma("unroll")                                                     \
      for (int zj = 0; zj < 4; ++zj)                                        \
        _Pragma("unroll")                                                   \
        for (int zr = 0; zr < 4; ++zr) acc[zi][zj][zr] = 0.f;               \
    const u8* wp = (WL);                                                    \
    _Pragma("unroll 1")                                                     \
    for (int c = 0; c < 4; ++c) {                                           \
      const u8* hc = hb + c * 128;                                          \
      i32x8 af0 = ld32(hc);                                                 \
      i32x8 af1 = ld32(hc + (size_t)16 * HSTRB);                            \
      i32x8 af2 = ld32(hc + (size_t)32 * HSTRB);                            \
      i32x8 af3 = ld32(hc + (size_t)48 * HSTRB);                            \
      i32x8 bA = ld32(wp);                                                  \
      i32x8 bB = ld32(wp + 2048);                                           \
      __builtin_amdgcn_sched_barrier(0);                                    \
      __builtin_amdgcn_s_setprio(1);                                        \
      acc[0][0] = MFMA_SC(af0, bA, acc[0][0]);                              \
      acc[1][0] = MFMA_SC(af1, bA, acc[1][0]);                              \
      acc[2][0] = MFMA_SC(af2, bA, acc[2][0]);                              \
      acc[3][0] = MFMA_SC(af3, bA, acc[3][0]);                              \
      acc[0][1] = MFMA_SC(af0, bB, acc[0][1]);                              \
      acc[1][1] = MFMA_SC(af1, bB, acc[1][1]);                              \
      acc[2][1] = MFMA_SC(af2, bB, acc[2][1]);                              \
      acc[3][1] = MFMA_SC(af3, bB, acc[3][1]);                              \
      __builtin_amdgcn_s_setprio(0);                                        \
      __builtin_amdgcn_sched_barrier(0);                                    \
      bA = ld32(wp + 4096);                                                 \
      bB = ld32(wp + 6144);                                                 \
      __builtin_amdgcn_sched_barrier(0);                                    \
      __builtin_amdgcn_s_setprio(1);                                        \
      acc[0][2] = MFMA_SC(af0, bA, acc[0][2]);                              \
      acc[1][2] = MFMA_SC(af1, bA, acc[1][2]);                              \
      acc[2][2] = MFMA_SC(af2, bA, acc[2][2]);                              \
      acc[3][2] = MFMA_SC(af3, bA, acc[3][2]);                              \
      acc[0][3] = MFMA_SC(af0, bB, acc[0][3]);                              \
      acc[1][3] = MFMA_SC(af1, bB, acc[1][3]);                              \
      acc[2][3] = MFMA_SC(af2, bB, acc[2][3]);                              \
      acc[3][3] = MFMA_SC(af3, bB, acc[3][3]);                              \
      __builtin_amdgcn_s_setprio(0);                                        \
      __builtin_amdgcn_sched_barrier(0);                                    \
      wp += 65536;                                                          \
    }                                                                       \
  }

// ---------------------------------------------------------------- prep
struct PrepArgs {
  const float *W1, *W2;
  u8 *W1s, *W2s;       // fp8 e4m3, K=128 frag-order: [4 chunks][8 waves][4 j][64 lanes][32 B]
  const float* c;
  u16* cb;
  const float *Wg0, *Wg1, *Wg2, *Wb0, *Wb1, *Wb2;
  const float *bg0, *bg1, *bg2;
  u16* Wpack;          // [6*512][64] bf16
  float* bias_pack;    // [3072]
  const float *x, *m1, *v1, *lg1, *be1;
  float *x_cur;
  const float *Wg3, *bg3, *Wb3;
  float *G3, *B3;
  const float *W0, *b0, *b1, *b2, *W3;
  float *E0, *E1, *E2;   // packed epilogue params
};
__global__ void prep_kernel(PrepArgs a) {
  int i = blockIdx.x * 256 + threadIdx.x;   // 0 .. 524287
  if (i < 512 * 512) {
    int n = i >> 9, k = i & 511;
    int c = k >> 7, q2 = (k >> 5) & 3, b = k & 31;          // K=128 chunk / lane-group / byte
    int w = n >> 6, j = (n >> 4) & 3, lr = n & 15;
    size_t d = (size_t)c * 65536 + (size_t)w * 8192 + (size_t)j * 2048 +
               (size_t)(q2 * 16 + lr) * 32 + b;
    a.W1s[d] = f2f8(a.W1[i]);
    a.W2s[d] = f2f8(a.W2[i]);
  }
  if (i < PTS * 64) a.cb[i] = f2bf(a.c[i]);
  if (i < 6 * 512 * 64) {
    int sec = i >> 15;
    int within = i & 32767;
    int o = within >> 6, k = within & 63;
    const float* src[6] = {a.Wg0, a.Wg1, a.Wg2, a.Wb0, a.Wb1, a.Wb2};
    a.Wpack[i] = f2bf(src[sec][o * 65 + 1 + k]);
  }
  if (i < 3072) {
    int sec = i >> 9, o = i & 511;
    const float* bgl[3] = {a.bg0, a.bg1, a.bg2};
    a.bias_pack[i] = (sec < 3) ? bgl[sec][o] : 0.f;
  }
  if (i < 512) {
    int o = i;
    a.E0[o * 8 + 0] = a.W0[o * 3];
    a.E0[o * 8 + 1] = a.W0[o * 3 + 1];
    a.E0[o * 8 + 2] = a.W0[o * 3 + 2];
    a.E0[o * 8 + 3] = a.b0[o];
    a.E0[o * 8 + 4] = a.Wg0[o * 65];
    a.E0[o * 8 + 5] = a.Wb0[o * 65];
    a.E0[o * 8 + 6] = 0.f; a.E0[o * 8 + 7] = 0.f;
    a.E1[o * 4 + 0] = a.b1[o];
    a.E1[o * 4 + 1] = a.Wg1[o * 65];
    a.E1[o * 4 + 2] = a.Wb1[o * 65];
    a.E1[o * 4 + 3] = 0.f;
    a.E2[o * 8 + 0] = a.b2[o];
    a.E2[o * 8 + 1] = a.Wg2[o * 65];
    a.E2[o * 8 + 2] = a.Wb2[o * 65];
    a.E2[o * 8 + 3] = a.W3[o];
    a.E2[o * 8 + 4] = a.W3[512 + o];
    a.E2[o * 8 + 5] = a.W3[1024 + o];
    a.E2[o * 8 + 6] = 0.f; a.E2[o * 8 + 7] = 0.f;
  }
  if (i < PTS * 3) {
    int d = i % 3;
    a.x_cur[i] = (a.x[i] - a.m1[d]) * __expf(a.lg1[d]) * rsqrtf(a.v1[d] + BN_EPS) + a.be1[d];
  }
  {
    int lane = threadIdx.x & 63;
    int p = (blockIdx.x * 256 + threadIdx.x) >> 6;   // 0..8191
    float cv = a.c[(size_t)p * 64 + lane];
    float ag[3], ab[3];
    #pragma unroll
    for (int o = 0; o < 3; ++o) {
      ag[o] = cv * a.Wg3[o * 65 + 1 + lane];
      ab[o] = cv * a.Wb3[o * 65 + 1 + lane];
    }
    #pragma unroll
    for (int off = 32; off > 0; off >>= 1) {
      #pragma unroll
      for (int o = 0; o < 3; ++o) {
        ag[o] += __shfl_xor(ag[o], off);
        ab[o] += __shfl_xor(ab[o], off);
      }
    }
    if (lane == 0) {
      #pragma unroll
      for (int o = 0; o < 3; ++o) {
        a.G3[p * 3 + o] = ag[o] + a.bg3[o];
        a.B3[p * 3 + o] = ab[o];
      }
    }
  }
}

// ---------------------------------------------------------------- gates GEMM (bf16, proven)
struct GatesGemmArgs {
  const u16 *A, *W;
  const float* bias;
  u16* GBi;                // [3][8192][1024] interleaved
};
__global__ __launch_bounds__(256) void gates_gemm(GatesGemmArgs a) {
  __shared__ u16 As[128 * 32];
  __shared__ u16 Bs[128 * 32];
  int tid = threadIdx.x;
  int m0 = blockIdx.x * 128, n0 = blockIdx.y * 128;
  int wave = tid >> 6, lane = tid & 63;
  int wm = (wave & 1) * 64, wn = (wave >> 1) * 64;
  int lr = lane & 15, quad = lane >> 4;

  int rowS = tid >> 2, colS = (tid & 3) * 8;
  const u16* gA0 = a.A + (size_t)(m0 + rowS) * 64 + colS;
  const u16* gB0 = a.W + (size_t)(n0 + rowS) * 64 + colS;
  u16* sA0 = &As[tid * 8];
  u16* sA1 = &As[2048 + tid * 8];
  u16* sB0 = &Bs[tid * 8];
  u16* sB1 = &Bs[2048 + tid * 8];

  f32x4 acc[4][4];
  #pragma unroll
  for (int i = 0; i < 4; ++i)
    #pragma unroll
    for (int j = 0; j < 4; ++j)
      #pragma unroll
      for (int r = 0; r < 4; ++r) acc[i][j][r] = 0.f;

  for (int k0 = 0; k0 < 64; k0 += 32) {
    if (k0) __syncthreads();
    gl2lds16(gA0 + k0, sA0);
    gl2lds16(gA0 + (size_t)64 * 64 + k0, sA1);
    gl2lds16(gB0 + k0, sB0);
    gl2lds16(gB0 + (size_t)64 * 64 + k0, sB1);
    __syncthreads();
    s16x8 af[4], bfr[4];
    #pragma unroll
    for (int i = 0; i < 4; ++i)
      af[i] = *(const s16x8*)&As[(wm + i * 16 + lr) * 32 + quad * 8];
    #pragma unroll
    for (int j = 0; j < 4; ++j)
      bfr[j] = *(const s16x8*)&Bs[(wn + j * 16 + lr) * 32 + quad * 8];
    #pragma unroll
    for (int i = 0; i < 4; ++i)
      #pragma unroll
      for (int j = 0; j < 4; ++j)
        acc[i][j] = __builtin_amdgcn_mfma_f32_16x16x32_bf16(af[i], bfr[j], acc[i][j], 0, 0, 0);
  }

  #pragma unroll
  for (int j = 0; j < 4; ++j) {
    int n = n0 + wn + j * 16 + lr;
    int sec = n >> 9, col = n & 511;
    int l = (sec < 3) ? sec : sec - 3;
    int off = col * 2 + ((sec < 3) ? 0 : 1);
    float bv = a.bias[n];
    u16* outp = a.GBi + (size_t)l * PTS * 1024 + off;
    #pragma unroll
    for (int i = 0; i < 4; ++i) {
      int mrow = m0 + wm + i * 16 + quad * 4;
      #pragma unroll
      for (int r = 0; r < 4; ++r)
        outp[(size_t)(mrow + r) * 1024] = f2bf(acc[i][j][r] + bv);
    }
  }
}

// ---------------------------------------------------------------- fused 12-stage flow kernel
struct FlowArgs {
  const float* sqrtT;
  const float *G3, *B3, *Wg3, *Wb3, *b3;
  const float* x0;                 // BN1-applied initial x
  const u16 *GBi0, *GBi1, *GBi2;   // interleaved gate tables [PTS][1024]
  const float *E0, *E1, *E2;       // packed params
  const u8 *W1s, *W2s;             // fp8 weights K=128 frag-order [4][8][4][64][32]
  const float *m2, *v2, *lg2, *be2;
  float* out_x;
  float* lp_state;
};

__global__ __launch_bounds__(512, 4) void flow_kernel(FlowArgs a) {
  __shared__ __align__(16) u8 Hs[64 * HSTRB];     // 33.8 KB (fp8 activations)
  __shared__ float xe[16][3];
  __shared__ float part[8][16][6];
  __shared__ float xs[16][3], kxs[16][3];
  __shared__ float kls[16], lps[16];
  __shared__ float g3s[16][3], b3s[16][3];

  int tid = threadIdx.x;
  int w = tid >> 6, lane = tid & 63, lr = lane & 15, quad = lane >> 4;
  int n0 = w * 64;
  int p0 = blockIdx.x * 16;
  float s0 = a.sqrtT[0];
  float dt = s0 * s0 * (1.f / 3.f);

  // wave-local W slice base pointers (K=128 frag-order)
  const u8* w1l = a.W1s + (size_t)w * 8192 + (size_t)lane * 32;
  const u8* w2l = a.W2s + (size_t)w * 8192 + (size_t)lane * 32;
  const u8* hb = (const u8*)Hs + (size_t)lr * HSTRB + quad * 32;

  float wg3r[3], wb3r[3], b3r[3];
  #pragma unroll
  for (int r = 0; r < 3; ++r) {
    wg3r[r] = a.Wg3[r * 65];
    wb3r[r] = a.Wb3[r * 65];
    b3r[r] = a.b3[r];
  }

  if (tid < 16) {
    int p = p0 + tid;
    #pragma unroll
    for (int r = 0; r < 3; ++r) {
      xs[tid][r] = a.x0[p * 3 + r];
      g3s[tid][r] = a.G3[p * 3 + r];
      b3s[tid][r] = a.B3[p * 3 + r];
    }
    lps[tid] = 0.f;
  }

  int pl0 = tid >> 5;
  int base_o = (tid & 31) * 16;
  const u16* g0row = a.GBi0 + (size_t)(p0 + pl0) * 1024 + 2 * base_o;

  #pragma unroll 1
  for (int s = 0; s < 12; ++s) {
    int sub = s & 3;
    float ts_cur = (float)(s >> 2) + ((sub == 0) ? 0.f : (sub == 3) ? 1.f : 0.5f);

    // issue L0 gate loads early (L2-hot after stage 0)
    u16x8 gc0 = *(const u16x8*)(g0row);
    u16x8 gc1 = *(const u16x8*)(g0row + 8);
    u16x8 gc2 = *(const u16x8*)(g0row + 16);
    u16x8 gc3 = *(const u16x8*)(g0row + 24);

    __syncthreads();   // s==0: init visible; s>0: part[] from prev stage visible

    // ---- fold previous stage (thread per point; all state in LDS)
    if (tid < 16) {
      float o0 = xs[tid][0], o1 = xs[tid][1], o2 = xs[tid][2];
      if (s > 0) {
        int m = (s - 1) & 3;
        float ts_prev = (float)((s - 1) >> 2) + ((m == 0) ? 0.f : (m == 3) ? 1.f : 0.5f);
        float tp = ts_prev * dt;
        float fr[6];
        #pragma unroll
        for (int r = 0; r < 6; ++r) {
          float sum = part[0][tid][r];
          #pragma unroll
          for (int ww = 1; ww < 8; ++ww) sum += part[ww][tid][r];
          fr[r] = sum;
        }
        float dx[3], gate[3];
        #pragma unroll
        for (int r = 0; r < 3; ++r) {
          gate[r] = sigf(g3s[tid][r] + tp * wg3r[r]);
          float bias = b3s[tid][r] + tp * wb3r[r];
          dx[r] = fmaf(fr[r] + b3r[r], gate[r], bias);
        }
        float klv = -(fr[3] * gate[0] + fr[4] * gate[1] + fr[5] * gate[2]);
        if (m == 0) {
          o0 += 0.5f * dt * dx[0]; o1 += 0.5f * dt * dx[1]; o2 += 0.5f * dt * dx[2];
          kxs[tid][0] = dx[0]; kxs[tid][1] = dx[1]; kxs[tid][2] = dx[2];
          kls[tid] = klv;
        } else if (m == 1) {
          o0 += 0.5f * dt * dx[0]; o1 += 0.5f * dt * dx[1]; o2 += 0.5f * dt * dx[2];
          kxs[tid][0] += 2.f * dx[0]; kxs[tid][1] += 2.f * dx[1]; kxs[tid][2] += 2.f * dx[2];
          kls[tid] += 2.f * klv;
        } else if (m == 2) {
          o0 += dt * dx[0]; o1 += dt * dx[1]; o2 += dt * dx[2];
          kxs[tid][0] += 2.f * dx[0]; kxs[tid][1] += 2.f * dx[1]; kxs[tid][2] += 2.f * dx[2];
          kls[tid] += 2.f * klv;
        } else {
          float sc = dt * (1.f / 6.f);
          o0 = xs[tid][0] + sc * (kxs[tid][0] + dx[0]);
          o1 = xs[tid][1] + sc * (kxs[tid][1] + dx[1]);
          o2 = xs[tid][2] + sc * (kxs[tid][2] + dx[2]);
          xs[tid][0] = o0; xs[tid][1] = o1; xs[tid][2] = o2;
          lps[tid] += sc * (kls[tid] + klv);
        }
      }
      xe[tid][0] = o0; xe[tid][1] = o1; xe[tid][2] = o2;
    }
    __syncthreads();

    float t = ts_cur * dt;

    // ---- layer0: 32 threads per point, 16 cols each -> H1 (fp8) in LDS
    {
      float x0v = xe[pl0][0], x1v = xe[pl0][1], x2v = xe[pl0][2];
      u16x8 gcv[4] = {gc0, gc1, gc2, gc3};
      #pragma unroll
      for (int cc = 0; cc < 4; ++cc) {
        u16x8 v = gcv[cc];
        float hk[4], d0k[4], d1k[4], d2k[4];
        #pragma unroll
        for (int k = 0; k < 4; ++k) {
          int o = base_o + cc * 4 + k;
          f32x4 e = *(const f32x4*)(a.E0 + (size_t)o * 8);
          f32x2 e2 = *(const f32x2*)(a.E0 + (size_t)o * 8 + 4);
          float u = fmaf(e[0], x0v, fmaf(e[1], x1v, e[2] * x2v)) + e[3];
          float gate = sigf(bf2f(v[2 * k]) + t * e2[0]);
          float bias = bf2f(v[2 * k + 1]) + t * e2[1];
          float z = fmaf(u, gate, bias);
          float h = fast_tanh(z);
          float wm = (1.f - h * h) * gate * TS;
          hk[k] = h;
          d0k[k] = wm * e[0];
          d1k[k] = wm * e[1];
          d2k[k] = wm * e[2];
        }
        size_t hbb = (size_t)(pl0 * 4) * HSTRB + base_o + cc * 4;
        *(unsigned*)(Hs + hbb) = pk4_f8(hk[0], hk[1], hk[2], hk[3]);
        *(unsigned*)(Hs + hbb + HSTRB) = pk4_f8(d0k[0], d0k[1], d0k[2], d0k[3]);
        *(unsigned*)(Hs + hbb + 2 * HSTRB) = pk4_f8(d1k[0], d1k[1], d1k[2], d1k[3]);
        *(unsigned*)(Hs + hbb + 3 * HSTRB) = pk4_f8(d2k[0], d2k[1], d2k[2], d2k[3]);
      }
    }
    __syncthreads();   // H1 visible to all waves

    // ---- GEMM1: MX fp8 K=128, j-pair schedule, acc in AGPRs
    f32x4 acc[4][4];
    MX_GEMM(w1l)

    // epilogue-1 gate dwords: loaded AFTER the GEMM (outside high-pressure region)
    unsigned g1v[4][4];
    #pragma unroll
    for (int j = 0; j < 4; ++j)
      #pragma unroll
      for (int i = 0; i < 4; ++i)
        g1v[j][i] = *(const unsigned*)(a.GBi1 + (size_t)(p0 + i * 4 + quad) * 1024 +
                                       2 * (n0 + j * 16 + lr));

    __syncthreads();   // all H1 reads done -> safe to overwrite

    // ---- epilogue1 -> H2 (fp8) in same LDS
    #pragma unroll
    for (int j = 0; j < 4; ++j) {
      int n = n0 + j * 16 + lr;
      f32x4 e1 = *(const f32x4*)(a.E1 + (size_t)n * 4);
      #pragma unroll
      for (int i = 0; i < 4; ++i) {
        unsigned d = g1v[j][i];
        float gate = sigf(bf2f((u16)(d & 0xffffu)) + t * e1[1]);
        float bias = bf2f((u16)(d >> 16)) + t * e1[2];
        f32x4 u = acc[i][j];
        float z = fmaf(u[0] + e1[0], gate, bias);
        float h = fast_tanh(z);
        float wmf = (1.f - h * h) * gate;
        int row = i * 16 + quad * 4;
        Hs[(size_t)row * HSTRB + n] = f2f8(h);
        Hs[(size_t)(row + 1) * HSTRB + n] = f2f8(u[1] * wmf);
        Hs[(size_t)(row + 2) * HSTRB + n] = f2f8(u[2] * wmf);
        Hs[(size_t)(row + 3) * HSTRB + n] = f2f8(u[3] * wmf);
      }
    }
    __syncthreads();   // H2 visible

    // ---- GEMM2
    MX_GEMM(w2l)

    unsigned g2v[4][4];
    #pragma unroll
    for (int j = 0; j < 4; ++j)
      #pragma unroll
      for (int i = 0; i < 4; ++i)
        g2v[j][i] = *(const unsigned*)(a.GBi2 + (size_t)(p0 + i * 4 + quad) * 1024 +
                                       2 * (n0 + j * 16 + lr));

    // ---- epilogue2: gate/tanh + project onto W3 -> 6 partials per point
    #pragma unroll
    for (int i = 0; i < 4; ++i) {
      float v0 = 0.f, v1 = 0.f, v2 = 0.f, v3 = 0.f, v4 = 0.f, v5 = 0.f;
      int pl = i * 4 + quad;
      #pragma unroll
      for (int j = 0; j < 4; ++j) {
        int n = n0 + j * 16 + lr;
        f32x4 ea = *(const f32x4*)(a.E2 + (size_t)n * 8);
        f32x2 eb = *(const f32x2*)(a.E2 + (size_t)n * 8 + 4);
        unsigned d = g2v[j][i];
        float gate = sigf(bf2f((u16)(d & 0xffffu)) + t * ea[1]);
        float bias = bf2f((u16)(d >> 16)) + t * ea[2];
        f32x4 u = acc[i][j];
        float z = fmaf(u[0] + ea[0], gate, bias);
        float h = fast_tanh(z);
        float wmf = (1.f - h * h) * gate;
        float w30 = ea[3], w31 = eb[0], w32 = eb[1];
        v0 = fmaf(h, w30, v0);
        v1 = fmaf(h, w31, v1);
        v2 = fmaf(h, w32, v2);
        v3 = fmaf(u[1] * wmf, w30, v3);
        v4 = fmaf(u[2] * wmf, w31, v4);
        v5 = fmaf(u[3] * wmf, w32, v5);
      }
      #pragma unroll
      for (int mask = 1; mask <= 8; mask <<= 1) {
        v0 += __shfl_xor(v0, mask);
        v1 += __shfl_xor(v1, mask);
        v2 += __shfl_xor(v2, mask);
        v3 += __shfl_xor(v3, mask);
        v4 += __shfl_xor(v4, mask);
        v5 += __shfl_xor(v5, mask);
      }
      // tangent streams carry TS scale through both GEMMs -> undo here
      float val = (lr == 0) ? v0 : (lr == 1) ? v1 : (lr == 2) ? v2
                : (lr == 3) ? v3 * (1.f / TS) : (lr == 4) ? v4 * (1.f / TS)
                : v5 * (1.f / TS);
      if (lr < 6) part[w][pl][lr] = val;
    }
  }  // stage loop

  __syncthreads();   // stage-11 partials visible

  // ---- final fold (mode 3 at t=T) + BN2 + store
  if (tid < 16) {
    int p = p0 + tid;
    float tp = 3.f * dt;
    float fr[6];
    #pragma unroll
    for (int r = 0; r < 6; ++r) {
      float sum = part[0][tid][r];
      #pragma unroll
      for (int ww = 1; ww < 8; ++ww) sum += part[ww][tid][r];
      fr[r] = sum;
    }
    float dx[3], gate[3];
    #pragma unroll
    for (int r = 0; r < 3; ++r) {
      gate[r] = sigf(g3s[tid][r] + tp * wg3r[r]);
      float bias = b3s[tid][r] + tp * wb3r[r];
      dx[r] = fmaf(fr[r] + b3r[r], gate[r], bias);
    }
    float klv = -(fr[3] * gate[0] + fr[4] * gate[1] + fr[5] * gate[2]);
    float sc = dt * (1.f / 6.f);
    #pragma unroll
    for (int r = 0; r < 3; ++r) {
      float xf = xs[tid][r] + sc * (kxs[tid][r] + dx[r]);
      a.out_x[p * 3 + r] =
          (xf - a.m2[r]) * __expf(a.lg2[r]) * rsqrtf(a.v2[r] + BN_EPS) + a.be2[r];
    }
    a.lp_state[p] = lps[tid] + sc * (kls[tid] + klv);
  }
}

__global__ void finish_lp(const float* __restrict__ lp_state,
                          const float* __restrict__ v1, const float* __restrict__ lg1,
                          const float* __restrict__ v2, const float* __restrict__ lg2,
                          float* __restrict__ out) {
  int b = blockIdx.x, tid = threadIdx.x;
  float s = 0.f;
  for (int n = tid; n < 2048; n += 256) s += lp_state[b * 2048 + n];
  __shared__ float red[256];
  red[tid] = s;
  __syncthreads();
  for (int w = 128; w > 0; w >>= 1) {
    if (tid < w) red[tid] += red[tid + w];
    __syncthreads();
  }
  if (tid == 0) {
    float ld = 0.f;
    for (int d = 0; d < 3; ++d) {
      ld += lg1[d] - 0.5f * logf(v1[d] + BN_EPS);
      ld += lg2[d] - 0.5f * logf(v2[d] + BN_EPS);
    }
    out[b] = red[0] - 2048.f * ld;
  }
}

// ---------------------------------------------------------------- launch
extern "C" void kernel_launch(void* const* d_in, const int* in_sizes, int n_in,
                              void* d_out, int out_size, void* d_ws, size_t ws_size,
                              hipStream_t stream) {
  const float* x        = (const float*)d_in[0];
  const float* c        = (const float*)d_in[1];
  const float* bn1_mean = (const float*)d_in[2];
  const float* bn1_var  = (const float*)d_in[3];
  const float* bn1_lg   = (const float*)d_in[4];
  const float* bn1_beta = (const float*)d_in[5];
  const float* bn2_mean = (const float*)d_in[6];
  const float* bn2_var  = (const float*)d_in[7];
  const float* bn2_lg   = (const float*)d_in[8];
  const float* bn2_beta = (const float*)d_in[9];
  const float* sqrtT    = (const float*)d_in[10];
  const float* W0  = (const float*)d_in[11];
  const float* b0  = (const float*)d_in[12];
  const float* Wg0 = (const float*)d_in[13];
  const float* bg0 = (const float*)d_in[14];
  const float* Wb0 = (const float*)d_in[15];
  const float* W1  = (const float*)d_in[16];
  const float* b1  = (const float*)d_in[17];
  const float* Wg1 = (const float*)d_in[18];
  const float* bg1 = (const float*)d_in[19];
  const float* Wb1 = (const float*)d_in[20];
  const float* W2  = (const float*)d_in[21];
  const float* b2  = (const float*)d_in[22];
  const float* Wg2 = (const float*)d_in[23];
  const float* bg2 = (const float*)d_in[24];
  const float* Wb2 = (const float*)d_in[25];
  const float* W3  = (const float*)d_in[26];
  const float* b3  = (const float*)d_in[27];
  const float* Wg3 = (const float*)d_in[28];
  const float* bg3 = (const float*)d_in[29];
  const float* Wb3 = (const float*)d_in[30];

  char* base = (char*)d_ws;
  size_t off = 0;
  auto alloc = [&](size_t bytes) -> void* {
    void* pp = base + off;
    off += (bytes + 255) & ~(size_t)255;
    return pp;
  };
  u8* W1s = (u8*)alloc((size_t)512 * 512);
  u8* W2s = (u8*)alloc((size_t)512 * 512);
  u16* cb  = (u16*)alloc((size_t)PTS * 64 * 2);
  u16* Wpack = (u16*)alloc((size_t)6 * 512 * 64 * 2);
  float* bias_pack = (float*)alloc((size_t)3072 * 4);
  u16* GBi = (u16*)alloc((size_t)3 * PTS * 1024 * 2);
  const size_t SZi = (size_t)PTS * 1024;
  u16* GBi0 = GBi;
  u16* GBi1 = GBi + SZi;
  u16* GBi2 = GBi + 2 * SZi;
  float* G3f = (float*)alloc((size_t)PTS * 3 * 4);
  float* B3f = (float*)alloc((size_t)PTS * 3 * 4);
  float* E0 = (float*)alloc((size_t)512 * 8 * 4);
  float* E1 = (float*)alloc((size_t)512 * 4 * 4);
  float* E2 = (float*)alloc((size_t)512 * 8 * 4);
  float* x_cur    = (float*)alloc((size_t)PTS * 3 * 4);
  float* lp_state = (float*)alloc((size_t)PTS * 4);
  (void)ws_size; (void)in_sizes; (void)n_in; (void)out_size;

  PrepArgs pa{W1, W2, W1s, W2s, c, cb, Wg0, Wg1, Wg2, Wb0, Wb1, Wb2,
              bg0, bg1, bg2, Wpack, bias_pack, x, bn1_mean, bn1_var,
              bn1_lg, bn1_beta, x_cur, Wg3, bg3, Wb3, G3f, B3f,
              W0, b0, b1, b2, W3, E0, E1, E2};
  prep_kernel<<<2048, 256, 0, stream>>>(pa);

  GatesGemmArgs gg{cb, Wpack, bias_pack, GBi};
  gates_gemm<<<dim3(64, 24), 256, 0, stream>>>(gg);

  FlowArgs fa{sqrtT, G3f, B3f, Wg3, Wb3, b3, x_cur, GBi0, GBi1, GBi2,
              E0, E1, E2, W1s, W2s, bn2_mean, bn2_var, bn2_lg, bn2_beta,
              (float*)d_out, lp_state};
  flow_kernel<<<PTS / 16, 512, 0, stream>>>(fa);

  finish_lp<<<4, 256, 0, stream>>>(lp_state, bn1_var, bn1_lg, bn2_var, bn2_lg,
                                   (float*)d_out + PTS * 3);
}

// Round 4
// 529.636 us; speedup vs baseline: 4.1943x; 1.0646x over previous
//
#include <hip/hip_runtime.h>
#include <hip/hip_fp8.h>

#define PTS 8192          // B*N = 4*2048 points
#define HDIM 512
#define BN_EPS 1e-4f
#define HSTRB 528         // LDS row stride in BYTES (fp8 cols)
#define TS 256.0f         // tangent-stream scale (keeps JVP streams out of e4m3 subnormals)
#define SCL1 0x7f7f7f7f   // E8M0 identity scale (1.0) for every 32-elem block

typedef unsigned short u16;
typedef unsigned char u8;
typedef long long i64;
typedef u16 u16x8 __attribute__((ext_vector_type(8)));
typedef short s16x8 __attribute__((ext_vector_type(8)));
typedef float f32x4 __attribute__((ext_vector_type(4)));
typedef float f32x2 __attribute__((ext_vector_type(2)));
typedef int i32x4 __attribute__((ext_vector_type(4)));
typedef int i32x8 __attribute__((ext_vector_type(8)));

__device__ __forceinline__ float bf2f(u16 u) {
  unsigned x = ((unsigned)u) << 16;
  return __builtin_bit_cast(float, x);
}
__device__ __forceinline__ u16 f2bf(float f) {
  unsigned x = __builtin_bit_cast(unsigned, f);
  x += 0x7fffu + ((x >> 16) & 1u);
  return (u16)(x >> 16);
}
// native HW fp8 convert (v_cvt_pk_fp8_f32; OCP e4m3 on gfx950)
__device__ __forceinline__ u8 f2f8(float x) {
  int v = __builtin_amdgcn_cvt_pk_fp8_f32(x, x, 0, false);
  return (u8)(v & 0xff);
}
__device__ __forceinline__ unsigned pk4_f8(float a, float b, float c, float d) {
  int v = __builtin_amdgcn_cvt_pk_fp8_f32(a, b, 0, false);
  v = __builtin_amdgcn_cvt_pk_fp8_f32(c, d, v, true);
  return (unsigned)v;
}
__device__ __forceinline__ float sigf(float x) {
  return __builtin_amdgcn_rcpf(1.f + __expf(-x));
}
__device__ __forceinline__ float fast_tanh(float x) {
  float e = __expf(2.f * x);
  return 1.f - 2.f * __builtin_amdgcn_rcpf(e + 1.f);
}
__device__ __forceinline__ void gl2lds16(const u16* g, u16* l) {
  __builtin_amdgcn_global_load_lds(
      (const __attribute__((address_space(1))) void*)g,
      (__attribute__((address_space(3))) void*)l, 16, 0, 0);
}
// 32B vector built from two 16B loads via clean SSA (no aliased alloca)
__device__ __forceinline__ i32x8 ld32(const u8* p) {
  i32x4 lo = *(const i32x4*)p;
  i32x4 hi = *(const i32x4*)(p + 16);
  return __builtin_shufflevector(lo, hi, 0, 1, 2, 3, 4, 5, 6, 7);
}

#define MFMA_SC(A, B, C) \
  __builtin_amdgcn_mfma_scale_f32_16x16x128_f8f6f4((A), (B), (C), 0, 0, 0, SCL1, 0, SCL1)

// MX K=128 GEMM, j-pair B schedule.  VGPR budget: af0..af3 (32) + bA,bB (16) +
// addressing (~10) < 64; acc[4][4] lives in AGPRs.  sched_barrier(0) (intrinsic,
// NO memory semantics) pins the B reloads below the preceding MFMA cluster.
// Proven spill-free at VGPR_Count=64 in round 3.
#define MX_GEMM(WL, HB)                                                     \
  {                                                                         \
    _Pragma("unroll")                                                       \
    for (int zi = 0; zi < 4; ++zi)                                          \
      _Pragma("unroll")                                                     \
      for (int zj = 0; zj < 4; ++zj)                                        \
        _Pragma("unroll")                                                   \
        for (int zr = 0; zr < 4; ++zr) acc[zi][zj][zr] = 0.f;               \
    const u8* wp = (WL);                                                    \
    _Pragma("unroll 1")                                                     \
    for (int c = 0; c < 4; ++c) {                                           \
      const u8* hc = (HB) + c * 128;                                        \
      i32x8 af0 = ld32(hc);                                                 \
      i32x8 af1 = ld32(hc + (size_t)16 * HSTRB);                            \
      i32x8 af2 = ld32(hc + (size_t)32 * HSTRB);                            \
      i32x8 af3 = ld32(hc + (size_t)48 * HSTRB);                            \
      i32x8 bA = ld32(wp);                                                  \
      i32x8 bB = ld32(wp + 2048);                                           \
      __builtin_amdgcn_sched_barrier(0);                                    \
      __builtin_amdgcn_s_setprio(1);                                        \
      acc[0][0] = MFMA_SC(af0, bA, acc[0][0]);                              \
      acc[1][0] = MFMA_SC(af1, bA, acc[1][0]);                              \
      acc[2][0] = MFMA_SC(af2, bA, acc[2][0]);                              \
      acc[3][0] = MFMA_SC(af3, bA, acc[3][0]);                              \
      acc[0][1] = MFMA_SC(af0, bB, acc[0][1]);                              \
      acc[1][1] = MFMA_SC(af1, bB, acc[1][1]);                              \
      acc[2][1] = MFMA_SC(af2, bB, acc[2][1]);                              \
      acc[3][1] = MFMA_SC(af3, bB, acc[3][1]);                              \
      __builtin_amdgcn_s_setprio(0);                                        \
      __builtin_amdgcn_sched_barrier(0);                                    \
      bA = ld32(wp + 4096);                                                 \
      bB = ld32(wp + 6144);                                                 \
      __builtin_amdgcn_sched_barrier(0);                                    \
      __builtin_amdgcn_s_setprio(1);                                        \
      acc[0][2] = MFMA_SC(af0, bA, acc[0][2]);                              \
      acc[1][2] = MFMA_SC(af1, bA, acc[1][2]);                              \
      acc[2][2] = MFMA_SC(af2, bA, acc[2][2]);                              \
      acc[3][2] = MFMA_SC(af3, bA, acc[3][2]);                              \
      acc[0][3] = MFMA_SC(af0, bB, acc[0][3]);                              \
      acc[1][3] = MFMA_SC(af1, bB, acc[1][3]);                              \
      acc[2][3] = MFMA_SC(af2, bB, acc[2][3]);                              \
      acc[3][3] = MFMA_SC(af3, bB, acc[3][3]);                              \
      __builtin_amdgcn_s_setprio(0);                                        \
      __builtin_amdgcn_sched_barrier(0);                                    \
      wp += 65536;                                                          \
    }                                                                       \
  }

// ---------------------------------------------------------------- prep
struct PrepArgs {
  const float *W1, *W2;
  u8 *W1s, *W2s;       // fp8 e4m3, K=128 frag-order: [4 chunks][8 waves][4 j][64 lanes][32 B]
  const float* c;
  u16* cb;
  const float *Wg0, *Wg1, *Wg2, *Wb0, *Wb1, *Wb2;
  const float *bg0, *bg1, *bg2;
  u16* Wpack;          // [6*512][64] bf16
  float* bias_pack;    // [3072]
  const float *x, *m1, *v1, *lg1, *be1;
  float *x_cur;
  const float *Wg3, *bg3, *Wb3;
  float *G3, *B3;
  const float *W0, *b0, *b1, *b2, *W3;
  float *E0, *E1, *E2;   // packed epilogue params
};
__global__ void prep_kernel(PrepArgs a) {
  int i = blockIdx.x * 256 + threadIdx.x;   // 0 .. 524287
  if (i < 512 * 512) {
    int n = i >> 9, k = i & 511;
    int c = k >> 7, q2 = (k >> 5) & 3, b = k & 31;          // K=128 chunk / lane-group / byte
    int w = n >> 6, j = (n >> 4) & 3, lr = n & 15;
    size_t d = (size_t)c * 65536 + (size_t)w * 8192 + (size_t)j * 2048 +
               (size_t)(q2 * 16 + lr) * 32 + b;
    a.W1s[d] = f2f8(a.W1[i]);
    a.W2s[d] = f2f8(a.W2[i]);
  }
  if (i < PTS * 64) a.cb[i] = f2bf(a.c[i]);
  if (i < 6 * 512 * 64) {
    int sec = i >> 15;
    int within = i & 32767;
    int o = within >> 6, k = within & 63;
    const float* src[6] = {a.Wg0, a.Wg1, a.Wg2, a.Wb0, a.Wb1, a.Wb2};
    a.Wpack[i] = f2bf(src[sec][o * 65 + 1 + k]);
  }
  if (i < 3072) {
    int sec = i >> 9, o = i & 511;
    const float* bgl[3] = {a.bg0, a.bg1, a.bg2};
    a.bias_pack[i] = (sec < 3) ? bgl[sec][o] : 0.f;
  }
  if (i < 512) {
    int o = i;
    a.E0[o * 8 + 0] = a.W0[o * 3];
    a.E0[o * 8 + 1] = a.W0[o * 3 + 1];
    a.E0[o * 8 + 2] = a.W0[o * 3 + 2];
    a.E0[o * 8 + 3] = a.b0[o];
    a.E0[o * 8 + 4] = a.Wg0[o * 65];
    a.E0[o * 8 + 5] = a.Wb0[o * 65];
    a.E0[o * 8 + 6] = 0.f; a.E0[o * 8 + 7] = 0.f;
    a.E1[o * 4 + 0] = a.b1[o];
    a.E1[o * 4 + 1] = a.Wg1[o * 65];
    a.E1[o * 4 + 2] = a.Wb1[o * 65];
    a.E1[o * 4 + 3] = 0.f;
    a.E2[o * 8 + 0] = a.b2[o];
    a.E2[o * 8 + 1] = a.Wg2[o * 65];
    a.E2[o * 8 + 2] = a.Wb2[o * 65];
    a.E2[o * 8 + 3] = a.W3[o];
    a.E2[o * 8 + 4] = a.W3[512 + o];
    a.E2[o * 8 + 5] = a.W3[1024 + o];
    a.E2[o * 8 + 6] = 0.f; a.E2[o * 8 + 7] = 0.f;
  }
  if (i < PTS * 3) {
    int d = i % 3;
    a.x_cur[i] = (a.x[i] - a.m1[d]) * __expf(a.lg1[d]) * rsqrtf(a.v1[d] + BN_EPS) + a.be1[d];
  }
  {
    int lane = threadIdx.x & 63;
    int p = (blockIdx.x * 256 + threadIdx.x) >> 6;   // 0..8191
    float cv = a.c[(size_t)p * 64 + lane];
    float ag[3], ab[3];
    #pragma unroll
    for (int o = 0; o < 3; ++o) {
      ag[o] = cv * a.Wg3[o * 65 + 1 + lane];
      ab[o] = cv * a.Wb3[o * 65 + 1 + lane];
    }
    #pragma unroll
    for (int off = 32; off > 0; off >>= 1) {
      #pragma unroll
      for (int o = 0; o < 3; ++o) {
        ag[o] += __shfl_xor(ag[o], off);
        ab[o] += __shfl_xor(ab[o], off);
      }
    }
    if (lane == 0) {
      #pragma unroll
      for (int o = 0; o < 3; ++o) {
        a.G3[p * 3 + o] = ag[o] + a.bg3[o];
        a.B3[p * 3 + o] = ab[o];
      }
    }
  }
}

// ---------------------------------------------------------------- gates GEMM (bf16, proven)
struct GatesGemmArgs {
  const u16 *A, *W;
  const float* bias;
  u16* GBi;                // [3][8192][1024] interleaved
};
__global__ __launch_bounds__(256) void gates_gemm(GatesGemmArgs a) {
  __shared__ u16 As[128 * 32];
  __shared__ u16 Bs[128 * 32];
  int tid = threadIdx.x;
  int m0 = blockIdx.x * 128, n0 = blockIdx.y * 128;
  int wave = tid >> 6, lane = tid & 63;
  int wm = (wave & 1) * 64, wn = (wave >> 1) * 64;
  int lr = lane & 15, quad = lane >> 4;

  int rowS = tid >> 2, colS = (tid & 3) * 8;
  const u16* gA0 = a.A + (size_t)(m0 + rowS) * 64 + colS;
  const u16* gB0 = a.W + (size_t)(n0 + rowS) * 64 + colS;
  u16* sA0 = &As[tid * 8];
  u16* sA1 = &As[2048 + tid * 8];
  u16* sB0 = &Bs[tid * 8];
  u16* sB1 = &Bs[2048 + tid * 8];

  f32x4 acc[4][4];
  #pragma unroll
  for (int i = 0; i < 4; ++i)
    #pragma unroll
    for (int j = 0; j < 4; ++j)
      #pragma unroll
      for (int r = 0; r < 4; ++r) acc[i][j][r] = 0.f;

  for (int k0 = 0; k0 < 64; k0 += 32) {
    if (k0) __syncthreads();
    gl2lds16(gA0 + k0, sA0);
    gl2lds16(gA0 + (size_t)64 * 64 + k0, sA1);
    gl2lds16(gB0 + k0, sB0);
    gl2lds16(gB0 + (size_t)64 * 64 + k0, sB1);
    __syncthreads();
    s16x8 af[4], bfr[4];
    #pragma unroll
    for (int i = 0; i < 4; ++i)
      af[i] = *(const s16x8*)&As[(wm + i * 16 + lr) * 32 + quad * 8];
    #pragma unroll
    for (int j = 0; j < 4; ++j)
      bfr[j] = *(const s16x8*)&Bs[(wn + j * 16 + lr) * 32 + quad * 8];
    #pragma unroll
    for (int i = 0; i < 4; ++i)
      #pragma unroll
      for (int j = 0; j < 4; ++j)
        acc[i][j] = __builtin_amdgcn_mfma_f32_16x16x32_bf16(af[i], bfr[j], acc[i][j], 0, 0, 0);
  }

  #pragma unroll
  for (int j = 0; j < 4; ++j) {
    int n = n0 + wn + j * 16 + lr;
    int sec = n >> 9, col = n & 511;
    int l = (sec < 3) ? sec : sec - 3;
    int off = col * 2 + ((sec < 3) ? 0 : 1);
    float bv = a.bias[n];
    u16* outp = a.GBi + (size_t)l * PTS * 1024 + off;
    #pragma unroll
    for (int i = 0; i < 4; ++i) {
      int mrow = m0 + wm + i * 16 + quad * 4;
      #pragma unroll
      for (int r = 0; r < 4; ++r)
        outp[(size_t)(mrow + r) * 1024] = f2bf(acc[i][j][r] + bv);
    }
  }
}

// ---------------------------------------------------------------- fused 12-stage flow kernel
// 512 blocks x 512 threads; block owns 16 points for the whole RK4 integration.
// Round-4 restructure: double-buffered H LDS (HsA: H1/GEMM1, HsB: H2/GEMM2) ->
// NO barrier between GEMM and its epilogue (waves drift, MFMA||VALU overlap);
// redundant per-thread fold (each thread folds its own point; tid&31==0 updates
// RK state) -> the 16-thread serial fold phase and 2 barriers are gone.
// 3 barriers/stage (was 5).  xs is a 2-entry ping-pong to avoid the read/write
// race at step-completing folds.
struct FlowArgs {
  const float* sqrtT;
  const float *G3, *B3, *Wg3, *Wb3, *b3;
  const float* x0;                 // BN1-applied initial x
  const u16 *GBi0, *GBi1, *GBi2;   // interleaved gate tables [PTS][1024]
  const float *E0, *E1, *E2;       // packed params
  const u8 *W1s, *W2s;             // fp8 weights K=128 frag-order [4][8][4][64][32]
  const float *m2, *v2, *lg2, *be2;
  float* out_x;
  float* lp_state;
};

__global__ __launch_bounds__(512, 4) void flow_kernel(FlowArgs a) {
  __shared__ __align__(16) u8 HsA[64 * HSTRB];    // 33 KB: H1 (fp8)
  __shared__ __align__(16) u8 HsB[64 * HSTRB];    // 33 KB: H2 (fp8)
  __shared__ float part[8][16][8];                // padded to 8 for f32x4 reads
  __shared__ float xs[2][16][3], kxs[16][3];
  __shared__ float kls[16], lps[16];
  __shared__ float g3s[16][3], b3s[16][3];

  int tid = threadIdx.x;
  int w = tid >> 6, lane = tid & 63, lr = lane & 15, quad = lane >> 4;
  int n0 = w * 64;
  int p0 = blockIdx.x * 16;
  int pl0 = tid >> 5;                 // this thread's point (0..15)
  int base_o = (tid & 31) * 16;
  bool desig = (tid & 31) == 0;       // one state-updater per point
  float s0 = a.sqrtT[0];
  float dt = s0 * s0 * (1.f / 3.f);

  const u8* w1l = a.W1s + (size_t)w * 8192 + (size_t)lane * 32;
  const u8* w2l = a.W2s + (size_t)w * 8192 + (size_t)lane * 32;
  const u8* hbA = (const u8*)HsA + (size_t)lr * HSTRB + quad * 32;
  const u8* hbB = (const u8*)HsB + (size_t)lr * HSTRB + quad * 32;

  float wg3r[3], wb3r[3], b3r[3];
  #pragma unroll
  for (int r = 0; r < 3; ++r) {
    wg3r[r] = a.Wg3[r * 65];
    wb3r[r] = a.Wb3[r * 65];
    b3r[r] = a.b3[r];
  }

  // gate-row pointers (mutable vars so the "+v" opacity barrier can apply)
  const u16* g0p = a.GBi0 + (size_t)(p0 + pl0) * 1024 + 2 * base_o;
  const u16* g1p = a.GBi1 + (size_t)(p0 + quad) * 1024 + 2 * (n0 + lr);
  const u16* g2p = a.GBi2 + (size_t)(p0 + quad) * 1024 + 2 * (n0 + lr);

  if (desig) {
    #pragma unroll
    for (int r = 0; r < 3; ++r) {
      xs[0][pl0][r] = a.x0[(p0 + pl0) * 3 + r];
      g3s[pl0][r] = a.G3[(p0 + pl0) * 3 + r];
      b3s[pl0][r] = a.B3[(p0 + pl0) * 3 + r];
    }
    lps[pl0] = 0.f;
  }
  // L0 gate dwords for stage 0 (stage-invariant data; reloaded per stage in (C))
  u16x8 gc0 = *(const u16x8*)(g0p);
  u16x8 gc1 = *(const u16x8*)(g0p + 8);
  u16x8 gc2 = *(const u16x8*)(g0p + 16);
  u16x8 gc3 = *(const u16x8*)(g0p + 24);
  __syncthreads();   // init visible

  #pragma unroll 1
  for (int s = 0; s < 12; ++s) {
    int sub = s & 3;
    float t = ((float)(s >> 2) + ((sub == 0) ? 0.f : (sub == 3) ? 1.f : 0.5f)) * dt;

    // ---- (A) redundant fold (own point) + layer0 -> HsA
    float o0, o1, o2;
    if (s == 0) {
      o0 = xs[0][pl0][0]; o1 = xs[0][pl0][1]; o2 = xs[0][pl0][2];
    } else {
      int m = (s - 1) & 3, q = (s - 1) >> 2;
      float tp = ((float)q + ((m == 0) ? 0.f : (m == 3) ? 1.f : 0.5f)) * dt;
      float fr0 = 0.f, fr1 = 0.f, fr2 = 0.f, fr3 = 0.f, fr4 = 0.f, fr5 = 0.f;
      #pragma unroll
      for (int ww = 0; ww < 8; ++ww) {
        f32x4 pa = *(const f32x4*)&part[ww][pl0][0];
        f32x2 pb = *(const f32x2*)&part[ww][pl0][4];
        fr0 += pa[0]; fr1 += pa[1]; fr2 += pa[2];
        fr3 += pa[3]; fr4 += pb[0]; fr5 += pb[1];
      }
      float ga0 = sigf(g3s[pl0][0] + tp * wg3r[0]);
      float ga1 = sigf(g3s[pl0][1] + tp * wg3r[1]);
      float ga2 = sigf(g3s[pl0][2] + tp * wg3r[2]);
      float dx0 = fmaf(fr0 + b3r[0], ga0, b3s[pl0][0] + tp * wb3r[0]);
      float dx1 = fmaf(fr1 + b3r[1], ga1, b3s[pl0][1] + tp * wb3r[1]);
      float dx2 = fmaf(fr2 + b3r[2], ga2, b3s[pl0][2] + tp * wb3r[2]);
      float klv = -(fr3 * ga0 + fr4 * ga1 + fr5 * ga2);
      float bx0 = xs[q & 1][pl0][0];
      float bx1 = xs[q & 1][pl0][1];
      float bx2 = xs[q & 1][pl0][2];
      if (m == 3) {
        float sc = dt * (1.f / 6.f);
        o0 = bx0 + sc * (kxs[pl0][0] + dx0);
        o1 = bx1 + sc * (kxs[pl0][1] + dx1);
        o2 = bx2 + sc * (kxs[pl0][2] + dx2);
        if (desig) {
          xs[(q + 1) & 1][pl0][0] = o0;
          xs[(q + 1) & 1][pl0][1] = o1;
          xs[(q + 1) & 1][pl0][2] = o2;
          lps[pl0] += sc * (kls[pl0] + klv);
        }
      } else {
        float cf = (m == 2) ? dt : 0.5f * dt;
        o0 = fmaf(cf, dx0, bx0);
        o1 = fmaf(cf, dx1, bx1);
        o2 = fmaf(cf, dx2, bx2);
        if (desig) {
          if (m == 0) {
            kxs[pl0][0] = dx0; kxs[pl0][1] = dx1; kxs[pl0][2] = dx2;
            kls[pl0] = klv;
          } else {
            kxs[pl0][0] += 2.f * dx0; kxs[pl0][1] += 2.f * dx1; kxs[pl0][2] += 2.f * dx2;
            kls[pl0] += 2.f * klv;
          }
        }
      }
    }

    // layer0: 32 threads per point, 16 cols each -> H1 (fp8) into HsA
    {
      u16x8 gcv[4] = {gc0, gc1, gc2, gc3};
      #pragma unroll
      for (int cc = 0; cc < 4; ++cc) {
        u16x8 v = gcv[cc];
        float hk[4], d0k[4], d1k[4], d2k[4];
        #pragma unroll
        for (int k = 0; k < 4; ++k) {
          int o = base_o + cc * 4 + k;
          f32x4 e = *(const f32x4*)(a.E0 + (size_t)o * 8);
          f32x2 e2 = *(const f32x2*)(a.E0 + (size_t)o * 8 + 4);
          float u = fmaf(e[0], o0, fmaf(e[1], o1, e[2] * o2)) + e[3];
          float gate = sigf(bf2f(v[2 * k]) + t * e2[0]);
          float bias = bf2f(v[2 * k + 1]) + t * e2[1];
          float z = fmaf(u, gate, bias);
          float h = fast_tanh(z);
          float wm = (1.f - h * h) * gate * TS;
          hk[k] = h;
          d0k[k] = wm * e[0];
          d1k[k] = wm * e[1];
          d2k[k] = wm * e[2];
        }
        size_t hbb = (size_t)(pl0 * 4) * HSTRB + base_o + cc * 4;
        *(unsigned*)(HsA + hbb) = pk4_f8(hk[0], hk[1], hk[2], hk[3]);
        *(unsigned*)(HsA + hbb + HSTRB) = pk4_f8(d0k[0], d0k[1], d0k[2], d0k[3]);
        *(unsigned*)(HsA + hbb + 2 * HSTRB) = pk4_f8(d1k[0], d1k[1], d1k[2], d1k[3]);
        *(unsigned*)(HsA + hbb + 3 * HSTRB) = pk4_f8(d2k[0], d2k[1], d2k[2], d2k[3]);
      }
    }
    __syncthreads();   // bar1: H1 visible

    // ---- (B) GEMM1 on HsA, then epilogue1 -> HsB (NO barrier between)
    f32x4 acc[4][4];
    MX_GEMM(w1l, hbA)

    asm("" : "+v"(g1p));   // register-only opacity: keep loads in-loop, post-GEMM
    unsigned g1v[4][4];
    #pragma unroll
    for (int j = 0; j < 4; ++j)
      #pragma unroll
      for (int i = 0; i < 4; ++i)
        g1v[j][i] = *(const unsigned*)(g1p + (size_t)i * 4096 + j * 32);

    #pragma unroll
    for (int j = 0; j < 4; ++j) {
      int n = n0 + j * 16 + lr;
      f32x4 e1 = *(const f32x4*)(a.E1 + (size_t)n * 4);
      #pragma unroll
      for (int i = 0; i < 4; ++i) {
        unsigned d = g1v[j][i];
        float gate = sigf(bf2f((u16)(d & 0xffffu)) + t * e1[1]);
        float bias = bf2f((u16)(d >> 16)) + t * e1[2];
        f32x4 u = acc[i][j];
        float z = fmaf(u[0] + e1[0], gate, bias);
        float h = fast_tanh(z);
        float wmf = (1.f - h * h) * gate;
        int row = i * 16 + quad * 4;
        HsB[(size_t)row * HSTRB + n] = f2f8(h);
        HsB[(size_t)(row + 1) * HSTRB + n] = f2f8(u[1] * wmf);
        HsB[(size_t)(row + 2) * HSTRB + n] = f2f8(u[2] * wmf);
        HsB[(size_t)(row + 3) * HSTRB + n] = f2f8(u[3] * wmf);
      }
    }
    __syncthreads();   // bar2: H2 visible

    // ---- (C) GEMM2 on HsB, then epilogue2 (NO barrier between)
    MX_GEMM(w2l, hbB)

    asm("" : "+v"(g2p));
    unsigned g2v[4][4];
    #pragma unroll
    for (int j = 0; j < 4; ++j)
      #pragma unroll
      for (int i = 0; i < 4; ++i)
        g2v[j][i] = *(const unsigned*)(g2p + (size_t)i * 4096 + j * 32);

    // reload L0 gates for next stage (latency hides under epilogue2)
    asm("" : "+v"(g0p));
    gc0 = *(const u16x8*)(g0p);
    gc1 = *(const u16x8*)(g0p + 8);
    gc2 = *(const u16x8*)(g0p + 16);
    gc3 = *(const u16x8*)(g0p + 24);

    #pragma unroll
    for (int i = 0; i < 4; ++i) {
      float v0 = 0.f, v1 = 0.f, v2 = 0.f, v3 = 0.f, v4 = 0.f, v5 = 0.f;
      int pl = i * 4 + quad;
      #pragma unroll
      for (int j = 0; j < 4; ++j) {
        int n = n0 + j * 16 + lr;
        f32x4 ea = *(const f32x4*)(a.E2 + (size_t)n * 8);
        f32x2 eb = *(const f32x2*)(a.E2 + (size_t)n * 8 + 4);
        unsigned d = g2v[j][i];
        float gate = sigf(bf2f((u16)(d & 0xffffu)) + t * ea[1]);
        float bias = bf2f((u16)(d >> 16)) + t * ea[2];
        f32x4 u = acc[i][j];
        float z = fmaf(u[0] + ea[0], gate, bias);
        float h = fast_tanh(z);
        float wmf = (1.f - h * h) * gate;
        float w30 = ea[3], w31 = eb[0], w32 = eb[1];
        v0 = fmaf(h, w30, v0);
        v1 = fmaf(h, w31, v1);
        v2 = fmaf(h, w32, v2);
        v3 = fmaf(u[1] * wmf, w30, v3);
        v4 = fmaf(u[2] * wmf, w31, v4);
        v5 = fmaf(u[3] * wmf, w32, v5);
      }
      #pragma unroll
      for (int mask = 1; mask <= 8; mask <<= 1) {
        v0 += __shfl_xor(v0, mask);
        v1 += __shfl_xor(v1, mask);
        v2 += __shfl_xor(v2, mask);
        v3 += __shfl_xor(v3, mask);
        v4 += __shfl_xor(v4, mask);
        v5 += __shfl_xor(v5, mask);
      }
      // tangent streams carry TS scale through both GEMMs -> undo here
      float val = (lr == 0) ? v0 : (lr == 1) ? v1 : (lr == 2) ? v2
                : (lr == 3) ? v3 * (1.f / TS) : (lr == 4) ? v4 * (1.f / TS)
                : v5 * (1.f / TS);
      if (lr < 6) part[w][pl][lr] = val;
    }
    __syncthreads();   // bar3: part visible (also frees HsA/HsB for next stage)
  }  // stage loop

  // ---- final fold (mode 3 at t=T) + BN2 + store (one thread per point)
  if (desig) {
    int p = p0 + pl0;
    float tp = 3.f * dt;
    float fr0 = 0.f, fr1 = 0.f, fr2 = 0.f, fr3 = 0.f, fr4 = 0.f, fr5 = 0.f;
    #pragma unroll
    for (int ww = 0; ww < 8; ++ww) {
      f32x4 pa = *(const f32x4*)&part[ww][pl0][0];
      f32x2 pb = *(const f32x2*)&part[ww][pl0][4];
      fr0 += pa[0]; fr1 += pa[1]; fr2 += pa[2];
      fr3 += pa[3]; fr4 += pb[0]; fr5 += pb[1];
    }
    float ga0 = sigf(g3s[pl0][0] + tp * wg3r[0]);
    float ga1 = sigf(g3s[pl0][1] + tp * wg3r[1]);
    float ga2 = sigf(g3s[pl0][2] + tp * wg3r[2]);
    float dx[3];
    dx[0] = fmaf(fr0 + b3r[0], ga0, b3s[pl0][0] + tp * wb3r[0]);
    dx[1] = fmaf(fr1 + b3r[1], ga1, b3s[pl0][1] + tp * wb3r[1]);
    dx[2] = fmaf(fr2 + b3r[2], ga2, b3s[pl0][2] + tp * wb3r[2]);
    float klv = -(fr3 * ga0 + fr4 * ga1 + fr5 * ga2);
    float sc = dt * (1.f / 6.f);
    #pragma unroll
    for (int r = 0; r < 3; ++r) {
      float xf = xs[0][pl0][r] + sc * (kxs[pl0][r] + dx[r]);
      a.out_x[p * 3 + r] =
          (xf - a.m2[r]) * __expf(a.lg2[r]) * rsqrtf(a.v2[r] + BN_EPS) + a.be2[r];
    }
    a.lp_state[p] = lps[pl0] + sc * (kls[pl0] + klv);
  }
}

__global__ void finish_lp(const float* __restrict__ lp_state,
                          const float* __restrict__ v1, const float* __restrict__ lg1,
                          const float* __restrict__ v2, const float* __restrict__ lg2,
                          float* __restrict__ out) {
  int b = blockIdx.x, tid = threadIdx.x;
  float s = 0.f;
  for (int n = tid; n < 2048; n += 256) s += lp_state[b * 2048 + n];
  __shared__ float red[256];
  red[tid] = s;
  __syncthreads();
  for (int w = 128; w > 0; w >>= 1) {
    if (tid < w) red[tid] += red[tid + w];
    __syncthreads();
  }
  if (tid == 0) {
    float ld = 0.f;
    for (int d = 0; d < 3; ++d) {
      ld += lg1[d] - 0.5f * logf(v1[d] + BN_EPS);
      ld += lg2[d] - 0.5f * logf(v2[d] + BN_EPS);
    }
    out[b] = red[0] - 2048.f * ld;
  }
}

// ---------------------------------------------------------------- launch
extern "C" void kernel_launch(void* const* d_in, const int* in_sizes, int n_in,
                              void* d_out, int out_size, void* d_ws, size_t ws_size,
                              hipStream_t stream) {
  const float* x        = (const float*)d_in[0];
  const float* c        = (const float*)d_in[1];
  const float* bn1_mean = (const float*)d_in[2];
  const float* bn1_var  = (const float*)d_in[3];
  const float* bn1_lg   = (const float*)d_in[4];
  const float* bn1_beta = (const float*)d_in[5];
  const float* bn2_mean = (const float*)d_in[6];
  const float* bn2_var  = (const float*)d_in[7];
  const float* bn2_lg   = (const float*)d_in[8];
  const float* bn2_beta = (const float*)d_in[9];
  const float* sqrtT    = (const float*)d_in[10];
  const float* W0  = (const float*)d_in[11];
  const float* b0  = (const float*)d_in[12];
  const float* Wg0 = (const float*)d_in[13];
  const float* bg0 = (const float*)d_in[14];
  const float* Wb0 = (const float*)d_in[15];
  const float* W1  = (const float*)d_in[16];
  const float* b1  = (const float*)d_in[17];
  const float* Wg1 = (const float*)d_in[18];
  const float* bg1 = (const float*)d_in[19];
  const float* Wb1 = (const float*)d_in[20];
  const float* W2  = (const float*)d_in[21];
  const float* b2  = (const float*)d_in[22];
  const float* Wg2 = (const float*)d_in[23];
  const float* bg2 = (const float*)d_in[24];
  const float* Wb2 = (const float*)d_in[25];
  const float* W3  = (const float*)d_in[26];
  const float* b3  = (const float*)d_in[27];
  const float* Wg3 = (const float*)d_in[28];
  const float* bg3 = (const float*)d_in[29];
  const float* Wb3 = (const float*)d_in[30];

  char* base = (char*)d_ws;
  size_t off = 0;
  auto alloc = [&](size_t bytes) -> void* {
    void* pp = base + off;
    off += (bytes + 255) & ~(size_t)255;
    return pp;
  };
  u8* W1s = (u8*)alloc((size_t)512 * 512);
  u8* W2s = (u8*)alloc((size_t)512 * 512);
  u16* cb  = (u16*)alloc((size_t)PTS * 64 * 2);
  u16* Wpack = (u16*)alloc((size_t)6 * 512 * 64 * 2);
  float* bias_pack = (float*)alloc((size_t)3072 * 4);
  u16* GBi = (u16*)alloc((size_t)3 * PTS * 1024 * 2);
  const size_t SZi = (size_t)PTS * 1024;
  u16* GBi0 = GBi;
  u16* GBi1 = GBi + SZi;
  u16* GBi2 = GBi + 2 * SZi;
  float* G3f = (float*)alloc((size_t)PTS * 3 * 4);
  float* B3f = (float*)alloc((size_t)PTS * 3 * 4);
  float* E0 = (float*)alloc((size_t)512 * 8 * 4);
  float* E1 = (float*)alloc((size_t)512 * 4 * 4);
  float* E2 = (float*)alloc((size_t)512 * 8 * 4);
  float* x_cur    = (float*)alloc((size_t)PTS * 3 * 4);
  float* lp_state = (float*)alloc((size_t)PTS * 4);
  (void)ws_size; (void)in_sizes; (void)n_in; (void)out_size;

  PrepArgs pa{W1, W2, W1s, W2s, c, cb, Wg0, Wg1, Wg2, Wb0, Wb1, Wb2,
              bg0, bg1, bg2, Wpack, bias_pack, x, bn1_mean, bn1_var,
              bn1_lg, bn1_beta, x_cur, Wg3, bg3, Wb3, G3f, B3f,
              W0, b0, b1, b2, W3, E0, E1, E2};
  prep_kernel<<<2048, 256, 0, stream>>>(pa);

  GatesGemmArgs gg{cb, Wpack, bias_pack, GBi};
  gates_gemm<<<dim3(64, 24), 256, 0, stream>>>(gg);

  FlowArgs fa{sqrtT, G3f, B3f, Wg3, Wb3, b3, x_cur, GBi0, GBi1, GBi2,
              E0, E1, E2, W1s, W2s, bn2_mean, bn2_var, bn2_lg, bn2_beta,
              (float*)d_out, lp_state};
  flow_kernel<<<PTS / 16, 512, 0, stream>>>(fa);

  finish_lp<<<4, 256, 0, stream>>>(lp_state, bn1_var, bn1_lg, bn2_var, bn2_lg,
                                   (float*)d_out + PTS * 3);
}